// Round 7
// baseline (973.228 us; speedup 1.0000x reference)
//
#include <hip/hip_runtime.h>

#define NEG_SLOPE 0.2f

typedef __attribute__((ext_vector_type(8))) short short8;
typedef __attribute__((ext_vector_type(4))) float floatx4;
typedef unsigned short ushort_t;

static __device__ __forceinline__ float leaky(float x){ return x > 0.f ? x : NEG_SLOPE * x; }

static __device__ __forceinline__ unsigned short bf16_rne(float x){
  unsigned u = __float_as_uint(x);
  unsigned r = (u + 0x7fffu + ((u >> 16) & 1u)) >> 16;
  return (unsigned short)r;
}
static __device__ __forceinline__ float bf16_to_f(unsigned short h){
  return __uint_as_float(((unsigned)h) << 16);
}

#define GLOAD_LDS16(g, l) \
  __builtin_amdgcn_global_load_lds((const __attribute__((address_space(1))) unsigned*)(g), \
                                   (__attribute__((address_space(3))) unsigned*)(l), 16, 0, 0)

// Pair-record layout (A operands of GEMMs): per row of logical width Kf,
// (Kf/16) slices of [hi x16 ushort (32B) | lo x16 ushort (32B)] = 64B/slice.
// Element k: slice k/16, hi at slice*32 + k%16, lo at +16. Record = 2*Kf ushort.

// ---------------- CSR build ----------------

__global__ void deg_kernel(const int* __restrict__ edges, int* __restrict__ deg, int E){
  int i = blockIdx.x * 256 + threadIdx.x;
  if (i < E) atomicAdd(&deg[edges[2*i + 1]], 1);
}

__global__ __launch_bounds__(256) void scan_part_kernel(const int* __restrict__ deg,
                                                        int* __restrict__ partial, int n){
  int i = blockIdx.x * 256 + threadIdx.x;
  int v = (i < n) ? deg[i] : 0;
  #pragma unroll
  for (int o = 32; o > 0; o >>= 1) v += __shfl_xor(v, o);
  __shared__ int ws[4];
  if ((threadIdx.x & 63) == 0) ws[threadIdx.x >> 6] = v;
  __syncthreads();
  if (threadIdx.x == 0) partial[blockIdx.x] = ws[0] + ws[1] + ws[2] + ws[3];
}

__global__ __launch_bounds__(256) void scan_top_kernel(int* __restrict__ partial, int nb){
  int t = threadIdx.x;
  int lane = t & 63, w = t >> 6;
  int v = (t < nb) ? partial[t] : 0;
  int sc = v;
  #pragma unroll
  for (int o = 1; o < 64; o <<= 1){
    int x = __shfl_up(sc, o);
    if (lane >= o) sc += x;
  }
  __shared__ int wt[4];
  if (lane == 63) wt[w] = sc;
  __syncthreads();
  int base = 0;
  for (int j = 0; j < w; j++) base += wt[j];
  if (t < nb) partial[t] = base + sc - v;
}

__global__ __launch_bounds__(256) void scan_fin_kernel(const int* __restrict__ deg,
    const int* __restrict__ partial, int* __restrict__ row_ptr, int* __restrict__ cursor,
    float* __restrict__ inv, int n){
  int b = blockIdx.x, t = threadIdx.x;
  int i = b * 256 + t;
  int lane = t & 63, w = t >> 6;
  int v = (i < n) ? deg[i] : 0;
  int sc = v;
  #pragma unroll
  for (int o = 1; o < 64; o <<= 1){
    int x = __shfl_up(sc, o);
    if (lane >= o) sc += x;
  }
  __shared__ int wt[4];
  if (lane == 63) wt[w] = sc;
  __syncthreads();
  int base = partial[b];
  for (int j = 0; j < w; j++) base += wt[j];
  int excl = base + sc - v;
  if (i < n){
    row_ptr[i] = excl;
    cursor[i]  = excl;
    inv[i] = (v > 0) ? 1.0f / (float)v : 0.0f;
    if (i == n - 1) row_ptr[n] = excl + v;
  }
}

__global__ void scatter_kernel(const int* __restrict__ edges, int* __restrict__ cursor,
                               int* __restrict__ col, int E){
  int i = blockIdx.x * 256 + threadIdx.x;
  if (i < E){
    int s = edges[2*i], d = edges[2*i + 1];
    int p = atomicAdd(&cursor[d], 1);
    col[p] = s;
  }
}

// Deterministic col order per row (harness re-validates after replays).
__global__ __launch_bounds__(256) void sortrows_kernel(const int* __restrict__ row_ptr,
                                                       int* __restrict__ col, int n){
  int gw = (blockIdx.x * 256 + threadIdx.x) >> 6;
  int lane = threadIdx.x & 63;
  if (gw >= n) return;
  int s = row_ptr[gw], e = row_ptr[gw + 1];
  int len = e - s;
  if (len <= 1) return;
  if (len <= 64){
    int v = (lane < len) ? col[s + lane] : 0x7fffffff;
    #pragma unroll
    for (int k = 2; k <= 64; k <<= 1){
      #pragma unroll
      for (int j = k >> 1; j > 0; j >>= 1){
        int o = __shfl_xor(v, j);
        bool dirUp = ((lane & k) == 0);
        bool takeMin = (((lane & j) == 0) == dirUp);
        v = takeMin ? min(v, o) : max(v, o);
      }
    }
    if (lane < len) col[s + lane] = v;
  } else if (lane == 0){
    for (int i = s + 1; i < e; ++i){
      int v = col[i];
      int j = i - 1;
      while (j >= s && col[j] > v){ col[j + 1] = col[j]; --j; }
      col[j + 1] = v;
    }
  }
}

// ---------------- W prep: transpose + split into bf16 hi/lo planes ----------------

__global__ void wprep_kernel(const float* __restrict__ W, ushort_t* __restrict__ hi,
                             ushort_t* __restrict__ lo, int K, int N){
  int i = blockIdx.x * 256 + threadIdx.x;
  if (i >= K * N) return;
  int k = i / N, n = i - k * N;
  float a = W[i];
  unsigned short h = bf16_rne(a);
  float r = a - bf16_to_f(h);
  hi[(size_t)n * K + k] = h;
  lo[(size_t)n * K + k] = bf16_rne(r);
}

// ---------------- MFMA GEMM ----------------
// A: pair-record rows (see top). Split-bf16 3-term: AhBh + AlBh + AhBl.
// 128x128 tile, 4 waves 2x2, BK=32, global_load_lds staging with XOR swizzle
// (linear LDS dest + inverse-swizzled global source). LDS logical chunk j of
// row r at byte (j*16)^((r&7)<<4); chunks 0..3 hi plane, 4..7 lo plane.

template<bool L1>
__global__ __launch_bounds__(256) void gemm_mfma_kernel(
    const ushort_t* __restrict__ A,
    const ushort_t* __restrict__ Bt_hi, const ushort_t* __restrict__ Bt_lo,
    const float* __restrict__ bias, const float* __restrict__ invv,
    float* __restrict__ Cf, ushort_t* __restrict__ Cp,
    int M, int K, int N){
  __shared__ ushort_t sA[128 * 64];
  __shared__ ushort_t sB[128 * 64];
  const int tid  = threadIdx.x;
  const int lane = tid & 63;
  const int wid  = tid >> 6;
  const int wrow = wid >> 1;
  const int wcol = wid & 1;
  const int br = blockIdx.x * 128;
  const int bc = blockIdx.y * 128;

  floatx4 acc[4][4];
  #pragma unroll
  for (int i = 0; i < 4; i++)
    #pragma unroll
    for (int j = 0; j < 4; j++) acc[i][j] = (floatx4){0.f, 0.f, 0.f, 0.f};

  char* pa = (char*)sA;
  char* pb = (char*)sB;
  const int g16 = (lane >> 4) << 4;
  const int r_st = tid >> 3;
  const int c_st = tid & 7;

  for (int k0 = 0; k0 < K; k0 += 32){
    #pragma unroll
    for (int q = 0; q < 4; q++){
      int r  = q * 32 + r_st;
      int sc = c_st ^ (r & 7);                // inverse-swizzled logical chunk
      {
        int grow = br + r;
        if (grow < M){
          // pair-record source offset for logical chunk sc
          int jl = sc & 3;
          int off = ((jl >> 1) << 5) + ((jl & 1) << 3) + ((sc >> 2) << 4); // ushorts
          const ushort_t* src = A + (size_t)grow * (2 * K) + k0 * 2 + off;
          GLOAD_LDS16(src, pa + q * 4096 + wid * 1024);
        }
      }
      {
        int gcol = bc + r;
        const ushort_t* srcB = (sc < 4) ? (Bt_hi + (size_t)gcol * K + k0 + sc * 8)
                                        : (Bt_lo + (size_t)gcol * K + k0 + (sc - 4) * 8);
        GLOAD_LDS16(srcB, pb + q * 4096 + wid * 1024);
      }
    }
    __syncthreads();
    short8 bh[4], bl[4];
    #pragma unroll
    for (int nf = 0; nf < 4; nf++){
      int coll = wcol * 64 + nf * 16 + (lane & 15);
      unsigned sw = (coll & 7) << 4;
      const char* pr = pb + coll * 128;
      bh[nf] = *(const short8*)(pr + ((g16) ^ sw));
      bl[nf] = *(const short8*)(pr + ((64 + g16) ^ sw));
    }
    #pragma unroll
    for (int mf = 0; mf < 4; mf++){
      int rowl = wrow * 64 + mf * 16 + (lane & 15);
      unsigned sw = (rowl & 7) << 4;
      const char* pr = pa + rowl * 128;
      short8 ah = *(const short8*)(pr + ((g16) ^ sw));
      short8 al = *(const short8*)(pr + ((64 + g16) ^ sw));
      #pragma unroll
      for (int nf = 0; nf < 4; nf++){
        acc[mf][nf] = __builtin_amdgcn_mfma_f32_16x16x32_bf16(ah, bh[nf], acc[mf][nf], 0, 0, 0);
        acc[mf][nf] = __builtin_amdgcn_mfma_f32_16x16x32_bf16(al, bh[nf], acc[mf][nf], 0, 0, 0);
        acc[mf][nf] = __builtin_amdgcn_mfma_f32_16x16x32_bf16(ah, bl[nf], acc[mf][nf], 0, 0, 0);
      }
    }
    __syncthreads();
  }

  const int r0 = br + wrow * 64;
  const int c0 = bc + wcol * 64;
  #pragma unroll
  for (int nf = 0; nf < 4; nf++){
    int col = c0 + nf * 16 + (lane & 15);
    float bv = bias[col];
    #pragma unroll
    for (int mf = 0; mf < 4; mf++){
      int rbase = r0 + mf * 16 + ((lane >> 4) << 2);
      #pragma unroll
      for (int j = 0; j < 4; j++){
        int r = rbase + j;
        if (r >= M) continue;
        float v;
        if (L1){
          float m = (invv[r] > 0.f) ? 1.f : 0.f;
          v = leaky(acc[mf][nf][j] + m * bv);
          unsigned short h = bf16_rne(v);
          unsigned short l = bf16_rne(v - bf16_to_f(h));
          size_t rb = (size_t)r * (2 * N);
          int o = ((col >> 4) << 5) + (col & 15);   // pair-record position
          Cp[rb + o]      = h;
          Cp[rb + o + 16] = l;
        } else {
          v = acc[mf][nf][j] + bv;
          Cf[(size_t)r * N + col] = v;
        }
      }
    }
  }
}

// ---------------- Sliced SpMM (XCD-affine column slices) ----------------
// One wave per (dst row, 16-col slice). 16 lanes x 4 edge-residues; scalar 4B
// loads (64B/group coalesced). Slice s runs on blocks with blockIdx%8 == s%8
// (round-robin block->XCD => each XCD touches a 3.2MB column slice -> L2-fits).
// EPI: 0 = pair out (inv), 1 = pair out (leaky(inv)), 2 = f32 out (inv).

template<int F, int EPI>
__global__ __launch_bounds__(256) void spmm_slice_kernel(const float* __restrict__ sup,
    const int* __restrict__ row_ptr, const int* __restrict__ col,
    const float* __restrict__ inv, void* __restrict__ outv, int n, int nRB){
  int bid = blockIdx.x;
  int s8  = bid & 7;
  int rem = bid >> 3;
  int epoch = (F == 256 && rem >= nRB) ? 1 : 0;
  int t = rem - epoch * nRB;
  int slice = epoch * 8 + s8;
  int row = t * 4 + (threadIdx.x >> 6);
  if (row >= n) return;
  int lane = threadIdx.x & 63;
  int cpos = lane & 15;
  int res  = lane >> 4;
  int s = row_ptr[row], e = row_ptr[row + 1];
  float ir = inv[row];
  const float* base = sup + slice * 16 + cpos;
  float acc = 0.f;
  for (int i = s + res; i < e; i += 4)
    acc += base[(size_t)col[i] * F];
  acc += __shfl_xor(acc, 16);
  acc += __shfl_xor(acc, 32);   // lanes 0-15 hold (v0+v1)+(v2+v3): deterministic
  if (lane < 16){
    float v = acc * ir;
    if (EPI == 2){
      ((float*)outv)[(size_t)row * F + slice * 16 + cpos] = v;
    } else {
      if (EPI == 1) v = leaky(v);
      ushort_t h = bf16_rne(v);
      ushort_t l = bf16_rne(v - bf16_to_f(h));
      ushort_t* op = (ushort_t*)outv + (size_t)row * (2 * F) + slice * 32 + cpos;
      op[0]  = h;
      op[16] = l;
    }
  }
}

// g (f32 [n][128], inv applied) -> out: L2 row-normalize. 2 rows/wave.
__global__ __launch_bounds__(256) void norm_fin_kernel(const float* __restrict__ g,
    float* __restrict__ out, int n){
  int gw = (blockIdx.x * 256 + threadIdx.x) >> 5;
  int lane = threadIdx.x & 31;
  if (gw >= n) return;
  float4 v = *(const float4*)(g + (size_t)gw * 128 + lane * 4);
  float ss = v.x*v.x + v.y*v.y + v.z*v.z + v.w*v.w;
  #pragma unroll
  for (int o = 16; o > 0; o >>= 1) ss += __shfl_xor(ss, o);
  float sc = 1.0f / fmaxf(sqrtf(ss), 1e-12f);
  float4 ov;
  ov.x = v.x * sc; ov.y = v.y * sc; ov.z = v.z * sc; ov.w = v.w * sc;
  *(float4*)(out + (size_t)gw * 128 + lane * 4) = ov;
}

// ---------------- launch ----------------

extern "C" void kernel_launch(void* const* d_in, const int* in_sizes, int n_in,
                              void* d_out, int out_size, void* d_ws, size_t ws_size,
                              hipStream_t stream){
  const float* x  = (const float*)d_in[0];
  const float* W1 = (const float*)d_in[1];
  const float* b1 = (const float*)d_in[2];
  const float* W2 = (const float*)d_in[3];
  const float* b2 = (const float*)d_in[4];
  const float* W3 = (const float*)d_in[5];
  const float* b3 = (const float*)d_in[6];
  const int* edges = (const int*)d_in[7];
  int N = in_sizes[0] / 128;
  int E = in_sizes[7] / 2;

  char* w = (char*)d_ws;
  size_t off = 0;
  auto alloc = [&](size_t bytes)->char*{
    char* p = w + off;
    off = (off + bytes + 255) & ~(size_t)255;
    return p;
  };
  int nBlocks = (N + 255) / 256;
  int*   deg     = (int*)  alloc((size_t)N * 4);
  float* inv     = (float*)alloc((size_t)N * 4);
  int*   row_ptr = (int*)  alloc(((size_t)N + 1) * 4);
  int*   cursor  = (int*)  alloc((size_t)N * 4);
  int*   colidx  = (int*)  alloc((size_t)E * 4);
  int*   partial = (int*)  alloc((size_t)nBlocks * 4);
  ushort_t* wt1h = (ushort_t*)alloc((size_t)128 * 256 * 2);
  ushort_t* wt1l = (ushort_t*)alloc((size_t)128 * 256 * 2);
  ushort_t* wt2h = (ushort_t*)alloc((size_t)256 * 256 * 2);
  ushort_t* wt2l = (ushort_t*)alloc((size_t)256 * 256 * 2);
  ushort_t* wt3h = (ushort_t*)alloc((size_t)256 * 128 * 2);
  ushort_t* wt3l = (ushort_t*)alloc((size_t)256 * 128 * 2);
  char* slabA = alloc((size_t)N * 512 * 2);   // 51.2 MB
  char* slabB = alloc((size_t)N * 512 * 2);   // 51.2 MB

  ushort_t* t_pair   = (ushort_t*)slabB;  // [N][256] pair-record
  ushort_t* h1_pair  = (ushort_t*)slabA;  // [N][512] pair-record
  float*    support2 = (float*)slabB;     // [N][256]
  ushort_t* h2_pair  = (ushort_t*)slabA;  // [N][512] pair-record
  float*    support3 = (float*)slabB;     // [N][128]
  float*    gbuf     = (float*)slabA;     // [N][128]

  hipMemsetAsync(deg, 0, (size_t)N * 4, stream);
  int gE = (E + 255) / 256;
  deg_kernel<<<gE, 256, 0, stream>>>(edges, deg, E);
  scan_part_kernel<<<nBlocks, 256, 0, stream>>>(deg, partial, N);
  scan_top_kernel<<<1, 256, 0, stream>>>(partial, nBlocks);
  scan_fin_kernel<<<nBlocks, 256, 0, stream>>>(deg, partial, row_ptr, cursor, inv, N);
  scatter_kernel<<<gE, 256, 0, stream>>>(edges, cursor, colidx, E);
  sortrows_kernel<<<(N * 64 + 255) / 256, 256, 0, stream>>>(row_ptr, colidx, N);

  wprep_kernel<<<(128*256 + 255)/256, 256, 0, stream>>>(W1, wt1h, wt1l, 128, 256);
  wprep_kernel<<<(256*256 + 255)/256, 256, 0, stream>>>(W2, wt2h, wt2l, 256, 256);
  wprep_kernel<<<(256*128 + 255)/256, 256, 0, stream>>>(W3, wt3h, wt3l, 256, 128);

  int gm = (N + 127) / 128;
  dim3 g12(gm, 2);
  dim3 g3 (gm, 1);
  int nRB = (N + 3) / 4;

  // layer 1 (reordered): t = A_hat x ; h1 = leaky(t@W1 + mask*b1)
  spmm_slice_kernel<128, 0><<<nRB * 8, 256, 0, stream>>>(x, row_ptr, colidx, inv, t_pair, N, nRB);
  gemm_mfma_kernel<true><<<g12, 256, 0, stream>>>(t_pair, wt1h, wt1l, b1, inv,
                                                  nullptr, h1_pair, N, 128, 256);
  // layer 2: support2 = h1@W2 + b2 ; h2 = leaky(A_hat support2)
  gemm_mfma_kernel<false><<<g12, 256, 0, stream>>>(h1_pair, wt2h, wt2l, b2, nullptr,
                                                   support2, nullptr, N, 256, 256);
  spmm_slice_kernel<256, 1><<<nRB * 16, 256, 0, stream>>>(support2, row_ptr, colidx, inv, h2_pair, N, nRB);
  // layer 3: support3 = h2@W3 + b3 ; out = normalize(A_hat support3)
  gemm_mfma_kernel<false><<<g3, 256, 0, stream>>>(h2_pair, wt3h, wt3l, b3, nullptr,
                                                  support3, nullptr, N, 256, 128);
  spmm_slice_kernel<128, 2><<<nRB * 8, 256, 0, stream>>>(support3, row_ptr, colidx, inv, gbuf, N, nRB);
  norm_fin_kernel<<<(N * 32 + 255) / 256, 256, 0, stream>>>(gbuf, (float*)d_out, N);
}

// Round 8
// 406.944 us; speedup vs baseline: 2.3916x; 2.3916x over previous
//
#include <hip/hip_runtime.h>

#define NEG_SLOPE 0.2f

typedef __attribute__((ext_vector_type(8))) short short8;
typedef __attribute__((ext_vector_type(4))) float floatx4;
typedef unsigned short ushort_t;

static __device__ __forceinline__ float leaky(float x){ return x > 0.f ? x : NEG_SLOPE * x; }

static __device__ __forceinline__ unsigned short bf16_rne(float x){
  unsigned u = __float_as_uint(x);
  unsigned r = (u + 0x7fffu + ((u >> 16) & 1u)) >> 16;
  return (unsigned short)r;
}
static __device__ __forceinline__ float bf16_to_f(unsigned short h){
  return __uint_as_float(((unsigned)h) << 16);
}

#define GLOAD_LDS16(g, l) \
  __builtin_amdgcn_global_load_lds((const __attribute__((address_space(1))) unsigned*)(g), \
                                   (__attribute__((address_space(3))) unsigned*)(l), 16, 0, 0)

// ---------------- CSR build ----------------

__global__ void deg_kernel(const int* __restrict__ edges, int* __restrict__ deg, int E){
  int i = blockIdx.x * 256 + threadIdx.x;
  if (i < E) atomicAdd(&deg[edges[2*i + 1]], 1);
}

__global__ __launch_bounds__(256) void scan_part_kernel(const int* __restrict__ deg,
                                                        int* __restrict__ partial, int n){
  int i = blockIdx.x * 256 + threadIdx.x;
  int v = (i < n) ? deg[i] : 0;
  #pragma unroll
  for (int o = 32; o > 0; o >>= 1) v += __shfl_xor(v, o);
  __shared__ int ws[4];
  if ((threadIdx.x & 63) == 0) ws[threadIdx.x >> 6] = v;
  __syncthreads();
  if (threadIdx.x == 0) partial[blockIdx.x] = ws[0] + ws[1] + ws[2] + ws[3];
}

__global__ __launch_bounds__(256) void scan_top_kernel(int* __restrict__ partial, int nb){
  int t = threadIdx.x;
  int lane = t & 63, w = t >> 6;
  int v = (t < nb) ? partial[t] : 0;
  int sc = v;
  #pragma unroll
  for (int o = 1; o < 64; o <<= 1){
    int x = __shfl_up(sc, o);
    if (lane >= o) sc += x;
  }
  __shared__ int wt[4];
  if (lane == 63) wt[w] = sc;
  __syncthreads();
  int base = 0;
  for (int j = 0; j < w; j++) base += wt[j];
  if (t < nb) partial[t] = base + sc - v;
}

__global__ __launch_bounds__(256) void scan_fin_kernel(const int* __restrict__ deg,
    const int* __restrict__ partial, int* __restrict__ row_ptr, int* __restrict__ cursor,
    float* __restrict__ inv, int n){
  int b = blockIdx.x, t = threadIdx.x;
  int i = b * 256 + t;
  int lane = t & 63, w = t >> 6;
  int v = (i < n) ? deg[i] : 0;
  int sc = v;
  #pragma unroll
  for (int o = 1; o < 64; o <<= 1){
    int x = __shfl_up(sc, o);
    if (lane >= o) sc += x;
  }
  __shared__ int wt[4];
  if (lane == 63) wt[w] = sc;
  __syncthreads();
  int base = partial[b];
  for (int j = 0; j < w; j++) base += wt[j];
  int excl = base + sc - v;
  if (i < n){
    row_ptr[i] = excl;
    cursor[i]  = excl;
    inv[i] = (v > 0) ? 1.0f / (float)v : 0.0f;
    if (i == n - 1) row_ptr[n] = excl + v;
  }
}

__global__ void scatter_kernel(const int* __restrict__ edges, int* __restrict__ cursor,
                               int* __restrict__ col, int E){
  int i = blockIdx.x * 256 + threadIdx.x;
  if (i < E){
    int s = edges[2*i], d = edges[2*i + 1];
    int p = atomicAdd(&cursor[d], 1);
    col[p] = s;
  }
}

// Deterministic col order per row (harness re-validates after replays; f32 sum
// order must be call-invariant). Wave-bitonic sort, all in registers.
__global__ __launch_bounds__(256) void sortrows_kernel(const int* __restrict__ row_ptr,
                                                       int* __restrict__ col, int n){
  int gw = (blockIdx.x * 256 + threadIdx.x) >> 6;
  int lane = threadIdx.x & 63;
  if (gw >= n) return;
  int s = row_ptr[gw], e = row_ptr[gw + 1];
  int len = e - s;
  if (len <= 1) return;
  if (len <= 64){
    int v = (lane < len) ? col[s + lane] : 0x7fffffff;
    #pragma unroll
    for (int k = 2; k <= 64; k <<= 1){
      #pragma unroll
      for (int j = k >> 1; j > 0; j >>= 1){
        int o = __shfl_xor(v, j);
        bool dirUp = ((lane & k) == 0);
        bool takeMin = (((lane & j) == 0) == dirUp);
        v = takeMin ? min(v, o) : max(v, o);
      }
    }
    if (lane < len) col[s + lane] = v;
  } else if (lane == 0){
    for (int i = s + 1; i < e; ++i){
      int v = col[i];
      int j = i - 1;
      while (j >= s && col[j] > v){ col[j + 1] = col[j]; --j; }
      col[j + 1] = v;
    }
  }
}

// ---------------- W prep (all 3 weights, one launch) ----------------
// W [K][N] f32 -> transposed bf16 hi/lo planes [N][K].

__global__ void wprep_all_kernel(const float* __restrict__ W1, const float* __restrict__ W2,
    const float* __restrict__ W3, ushort_t* __restrict__ h1, ushort_t* __restrict__ l1,
    ushort_t* __restrict__ h2, ushort_t* __restrict__ l2,
    ushort_t* __restrict__ h3, ushort_t* __restrict__ l3){
  int i = blockIdx.x * 256 + threadIdx.x;
  const float* W; ushort_t* hp; ushort_t* lp; int K, N, idx;
  if (i < 32768)      { W = W1; hp = h1; lp = l1; K = 128; N = 256; idx = i; }
  else if (i < 98304) { W = W2; hp = h2; lp = l2; K = 256; N = 256; idx = i - 32768; }
  else if (i < 131072){ W = W3; hp = h3; lp = l3; K = 256; N = 128; idx = i - 98304; }
  else return;
  int k = idx / N, n = idx - k * N;
  float a = W[idx];
  ushort_t h = bf16_rne(a);
  hp[(size_t)n * K + k] = h;
  lp[(size_t)n * K + k] = bf16_rne(a - bf16_to_f(h));
}

// ---------------- MFMA GEMM ----------------
// A: [M][2K] ushort plane rows (hi[0..K) | lo[K..2K)) -- preconverted.
// Split-bf16 3-term: AhBh + AlBh + AhBl, f32 accum.
// 128x128 tile, 4 waves 2x2, BK=32, global_load_lds staging with XOR swizzle
// (linear LDS dest + inverse-swizzled global source). LDS logical chunk j of
// row r at byte (j*16)^((r&7)<<4); chunks 0..3 hi plane, 4..7 lo plane.
// MODE: 0 = f32 out + bias; 1 = L1: pair out, leaky, bias masked by inv>0;
//       2 = bf16 out + bias.

template<int MODE>
__global__ __launch_bounds__(256) void gemm_mfma_kernel(
    const ushort_t* __restrict__ A,
    const ushort_t* __restrict__ Bt_hi, const ushort_t* __restrict__ Bt_lo,
    const float* __restrict__ bias, const float* __restrict__ invv,
    float* __restrict__ Cf, ushort_t* __restrict__ Cp,
    int M, int K, int N){
  __shared__ ushort_t sA[128 * 64];
  __shared__ ushort_t sB[128 * 64];
  const int tid  = threadIdx.x;
  const int lane = tid & 63;
  const int wid  = tid >> 6;
  const int wrow = wid >> 1;
  const int wcol = wid & 1;
  const int br = blockIdx.x * 128;
  const int bc = blockIdx.y * 128;

  floatx4 acc[4][4];
  #pragma unroll
  for (int i = 0; i < 4; i++)
    #pragma unroll
    for (int j = 0; j < 4; j++) acc[i][j] = (floatx4){0.f, 0.f, 0.f, 0.f};

  char* pa = (char*)sA;
  char* pb = (char*)sB;
  const int g16 = (lane >> 4) << 4;
  const int r_st = tid >> 3;
  const int c_st = tid & 7;

  for (int k0 = 0; k0 < K; k0 += 32){
    #pragma unroll
    for (int q = 0; q < 4; q++){
      int r  = q * 32 + r_st;
      int sc = c_st ^ (r & 7);                // inverse-swizzled logical chunk
      {
        int grow = br + r;
        if (grow < M){
          const ushort_t* src = A + (size_t)grow * (2 * K)
                                  + ((sc < 4) ? (k0 + sc * 8) : (K + k0 + (sc - 4) * 8));
          GLOAD_LDS16(src, pa + q * 4096 + wid * 1024);
        }
      }
      {
        int gcol = bc + r;
        const ushort_t* srcB = (sc < 4) ? (Bt_hi + (size_t)gcol * K + k0 + sc * 8)
                                        : (Bt_lo + (size_t)gcol * K + k0 + (sc - 4) * 8);
        GLOAD_LDS16(srcB, pb + q * 4096 + wid * 1024);
      }
    }
    __syncthreads();
    short8 bh[4], bl[4];
    #pragma unroll
    for (int nf = 0; nf < 4; nf++){
      int coll = wcol * 64 + nf * 16 + (lane & 15);
      unsigned sw = (coll & 7) << 4;
      const char* pr = pb + coll * 128;
      bh[nf] = *(const short8*)(pr + ((g16) ^ sw));
      bl[nf] = *(const short8*)(pr + ((64 + g16) ^ sw));
    }
    #pragma unroll
    for (int mf = 0; mf < 4; mf++){
      int rowl = wrow * 64 + mf * 16 + (lane & 15);
      unsigned sw = (rowl & 7) << 4;
      const char* pr = pa + rowl * 128;
      short8 ah = *(const short8*)(pr + ((g16) ^ sw));
      short8 al = *(const short8*)(pr + ((64 + g16) ^ sw));
      #pragma unroll
      for (int nf = 0; nf < 4; nf++){
        acc[mf][nf] = __builtin_amdgcn_mfma_f32_16x16x32_bf16(ah, bh[nf], acc[mf][nf], 0, 0, 0);
        acc[mf][nf] = __builtin_amdgcn_mfma_f32_16x16x32_bf16(al, bh[nf], acc[mf][nf], 0, 0, 0);
        acc[mf][nf] = __builtin_amdgcn_mfma_f32_16x16x32_bf16(ah, bl[nf], acc[mf][nf], 0, 0, 0);
      }
    }
    __syncthreads();
  }

  const int r0 = br + wrow * 64;
  const int c0 = bc + wcol * 64;
  #pragma unroll
  for (int nf = 0; nf < 4; nf++){
    int col = c0 + nf * 16 + (lane & 15);
    float bv = bias[col];
    #pragma unroll
    for (int mf = 0; mf < 4; mf++){
      int rbase = r0 + mf * 16 + ((lane >> 4) << 2);
      #pragma unroll
      for (int j = 0; j < 4; j++){
        int r = rbase + j;
        if (r >= M) continue;
        if (MODE == 1){
          float m = (invv[r] > 0.f) ? 1.f : 0.f;
          float v = leaky(acc[mf][nf][j] + m * bv);
          unsigned short h = bf16_rne(v);
          unsigned short l = bf16_rne(v - bf16_to_f(h));
          Cp[(size_t)r * (2 * N) + col]     = h;
          Cp[(size_t)r * (2 * N) + N + col] = l;
        } else if (MODE == 2){
          Cp[(size_t)r * N + col] = bf16_rne(acc[mf][nf][j] + bv);
        } else {
          Cf[(size_t)r * N + col] = acc[mf][nf][j] + bv;
        }
      }
    }
  }
}

// ---------------- SpMM kernels (CSR gather) ----------------

// x (f32 [n][128]) -> t pair (ushort [n][256]); t = inv * sum x[src]
// 2 rows per wave: 32 lanes/row, float4 (16B)/lane, unroll-4.
__global__ __launch_bounds__(256) void spmm128_pair_kernel(const float* __restrict__ x,
    const int* __restrict__ row_ptr, const int* __restrict__ col,
    const float* __restrict__ inv, ushort_t* __restrict__ out, int n){
  int gw = (blockIdx.x * 256 + threadIdx.x) >> 5;
  int lane = threadIdx.x & 31;
  if (gw >= n) return;
  int s = row_ptr[gw], e = row_ptr[gw + 1];
  float ir = inv[gw];
  int off = lane * 4;
  float4 a0 = make_float4(0.f,0.f,0.f,0.f), a1 = make_float4(0.f,0.f,0.f,0.f);
  float4 a2 = make_float4(0.f,0.f,0.f,0.f), a3 = make_float4(0.f,0.f,0.f,0.f);
  int i = s;
  for (; i + 3 < e; i += 4){
    int c0 = col[i], c1 = col[i+1], c2 = col[i+2], c3 = col[i+3];
    float4 v0 = *(const float4*)(x + (size_t)c0 * 128 + off);
    float4 v1 = *(const float4*)(x + (size_t)c1 * 128 + off);
    float4 v2 = *(const float4*)(x + (size_t)c2 * 128 + off);
    float4 v3 = *(const float4*)(x + (size_t)c3 * 128 + off);
    a0.x += v0.x; a0.y += v0.y; a0.z += v0.z; a0.w += v0.w;
    a1.x += v1.x; a1.y += v1.y; a1.z += v1.z; a1.w += v1.w;
    a2.x += v2.x; a2.y += v2.y; a2.z += v2.z; a2.w += v2.w;
    a3.x += v3.x; a3.y += v3.y; a3.z += v3.z; a3.w += v3.w;
  }
  for (; i < e; ++i){
    int c0 = col[i];
    float4 v0 = *(const float4*)(x + (size_t)c0 * 128 + off);
    a0.x += v0.x; a0.y += v0.y; a0.z += v0.z; a0.w += v0.w;
  }
  float f[4];
  f[0] = ((a0.x + a1.x) + (a2.x + a3.x)) * ir;
  f[1] = ((a0.y + a1.y) + (a2.y + a3.y)) * ir;
  f[2] = ((a0.z + a1.z) + (a2.z + a3.z)) * ir;
  f[3] = ((a0.w + a1.w) + (a2.w + a3.w)) * ir;
  ushort4 hv, lv;
  ushort_t h;
  h = bf16_rne(f[0]); hv.x = h; lv.x = bf16_rne(f[0] - bf16_to_f(h));
  h = bf16_rne(f[1]); hv.y = h; lv.y = bf16_rne(f[1] - bf16_to_f(h));
  h = bf16_rne(f[2]); hv.z = h; lv.z = bf16_rne(f[2] - bf16_to_f(h));
  h = bf16_rne(f[3]); hv.w = h; lv.w = bf16_rne(f[3] - bf16_to_f(h));
  *(ushort4*)(out + (size_t)gw * 256 + off)       = hv;
  *(ushort4*)(out + (size_t)gw * 256 + 128 + off) = lv;
}

// support2 (bf16 [n][256]) -> h pair (ushort [n][512]); h = leaky(inv * sum)
// 1 row per wave: 64 lanes, ushort4 (8B = 4 bf16)/lane, unroll-4, f32 accum.
__global__ __launch_bounds__(256) void spmm256b_leaky_pair_kernel(const ushort_t* __restrict__ sup,
    const int* __restrict__ row_ptr, const int* __restrict__ col,
    const float* __restrict__ inv, ushort_t* __restrict__ out, int n){
  int gw = (blockIdx.x * 256 + threadIdx.x) >> 6;
  int lane = threadIdx.x & 63;
  if (gw >= n) return;
  int s = row_ptr[gw], e = row_ptr[gw + 1];
  float ir = inv[gw];
  int off = lane * 4;
  float4 a0 = make_float4(0.f,0.f,0.f,0.f), a1 = make_float4(0.f,0.f,0.f,0.f);
  float4 a2 = make_float4(0.f,0.f,0.f,0.f), a3 = make_float4(0.f,0.f,0.f,0.f);
  int i = s;
  for (; i + 3 < e; i += 4){
    int c0 = col[i], c1 = col[i+1], c2 = col[i+2], c3 = col[i+3];
    ushort4 u0 = *(const ushort4*)(sup + (size_t)c0 * 256 + off);
    ushort4 u1 = *(const ushort4*)(sup + (size_t)c1 * 256 + off);
    ushort4 u2 = *(const ushort4*)(sup + (size_t)c2 * 256 + off);
    ushort4 u3 = *(const ushort4*)(sup + (size_t)c3 * 256 + off);
    a0.x += bf16_to_f(u0.x); a0.y += bf16_to_f(u0.y); a0.z += bf16_to_f(u0.z); a0.w += bf16_to_f(u0.w);
    a1.x += bf16_to_f(u1.x); a1.y += bf16_to_f(u1.y); a1.z += bf16_to_f(u1.z); a1.w += bf16_to_f(u1.w);
    a2.x += bf16_to_f(u2.x); a2.y += bf16_to_f(u2.y); a2.z += bf16_to_f(u2.z); a2.w += bf16_to_f(u2.w);
    a3.x += bf16_to_f(u3.x); a3.y += bf16_to_f(u3.y); a3.z += bf16_to_f(u3.z); a3.w += bf16_to_f(u3.w);
  }
  for (; i < e; ++i){
    int c0 = col[i];
    ushort4 u0 = *(const ushort4*)(sup + (size_t)c0 * 256 + off);
    a0.x += bf16_to_f(u0.x); a0.y += bf16_to_f(u0.y); a0.z += bf16_to_f(u0.z); a0.w += bf16_to_f(u0.w);
  }
  float f[4];
  f[0] = leaky(((a0.x + a1.x) + (a2.x + a3.x)) * ir);
  f[1] = leaky(((a0.y + a1.y) + (a2.y + a3.y)) * ir);
  f[2] = leaky(((a0.z + a1.z) + (a2.z + a3.z)) * ir);
  f[3] = leaky(((a0.w + a1.w) + (a2.w + a3.w)) * ir);
  ushort4 hv, lv;
  ushort_t h;
  h = bf16_rne(f[0]); hv.x = h; lv.x = bf16_rne(f[0] - bf16_to_f(h));
  h = bf16_rne(f[1]); hv.y = h; lv.y = bf16_rne(f[1] - bf16_to_f(h));
  h = bf16_rne(f[2]); hv.z = h; lv.z = bf16_rne(f[2] - bf16_to_f(h));
  h = bf16_rne(f[3]); hv.w = h; lv.w = bf16_rne(f[3] - bf16_to_f(h));
  *(ushort4*)(out + (size_t)gw * 512 + off)       = hv;
  *(ushort4*)(out + (size_t)gw * 512 + 256 + off) = lv;
}

// support3 (f32 [n][128]) -> out f32 [n][128]; inv-scale + L2 row-normalize
__global__ __launch_bounds__(256) void spmm_norm_kernel(const float* __restrict__ sup,
    const int* __restrict__ row_ptr, const int* __restrict__ col,
    const float* __restrict__ inv, float* __restrict__ out, int n){
  int gw = (blockIdx.x * 256 + threadIdx.x) >> 5;
  int lane = threadIdx.x & 31;
  if (gw >= n) return;
  int s = row_ptr[gw], e = row_ptr[gw + 1];
  float ir = inv[gw];
  int off = lane * 4;
  float4 a0 = make_float4(0.f,0.f,0.f,0.f), a1 = make_float4(0.f,0.f,0.f,0.f);
  float4 a2 = make_float4(0.f,0.f,0.f,0.f), a3 = make_float4(0.f,0.f,0.f,0.f);
  int i = s;
  for (; i + 3 < e; i += 4){
    int c0 = col[i], c1 = col[i+1], c2 = col[i+2], c3 = col[i+3];
    float4 v0 = *(const float4*)(sup + (size_t)c0 * 128 + off);
    float4 v1 = *(const float4*)(sup + (size_t)c1 * 128 + off);
    float4 v2 = *(const float4*)(sup + (size_t)c2 * 128 + off);
    float4 v3 = *(const float4*)(sup + (size_t)c3 * 128 + off);
    a0.x += v0.x; a0.y += v0.y; a0.z += v0.z; a0.w += v0.w;
    a1.x += v1.x; a1.y += v1.y; a1.z += v1.z; a1.w += v1.w;
    a2.x += v2.x; a2.y += v2.y; a2.z += v2.z; a2.w += v2.w;
    a3.x += v3.x; a3.y += v3.y; a3.z += v3.z; a3.w += v3.w;
  }
  for (; i < e; ++i){
    int c0 = col[i];
    float4 v0 = *(const float4*)(sup + (size_t)c0 * 128 + off);
    a0.x += v0.x; a0.y += v0.y; a0.z += v0.z; a0.w += v0.w;
  }
  float v0 = ((a0.x + a1.x) + (a2.x + a3.x)) * ir;
  float v1 = ((a0.y + a1.y) + (a2.y + a3.y)) * ir;
  float v2 = ((a0.z + a1.z) + (a2.z + a3.z)) * ir;
  float v3 = ((a0.w + a1.w) + (a2.w + a3.w)) * ir;
  float ss = v0*v0 + v1*v1 + v2*v2 + v3*v3;
  #pragma unroll
  for (int o = 16; o > 0; o >>= 1) ss += __shfl_xor(ss, o);
  float scale = 1.0f / fmaxf(sqrtf(ss), 1e-12f);
  float4 ov;
  ov.x = v0 * scale; ov.y = v1 * scale; ov.z = v2 * scale; ov.w = v3 * scale;
  *(float4*)(out + (size_t)gw * 128 + off) = ov;
}

// ---------------- launch ----------------

extern "C" void kernel_launch(void* const* d_in, const int* in_sizes, int n_in,
                              void* d_out, int out_size, void* d_ws, size_t ws_size,
                              hipStream_t stream){
  const float* x  = (const float*)d_in[0];
  const float* W1 = (const float*)d_in[1];
  const float* b1 = (const float*)d_in[2];
  const float* W2 = (const float*)d_in[3];
  const float* b2 = (const float*)d_in[4];
  const float* W3 = (const float*)d_in[5];
  const float* b3 = (const float*)d_in[6];
  const int* edges = (const int*)d_in[7];
  int N = in_sizes[0] / 128;
  int E = in_sizes[7] / 2;

  char* w = (char*)d_ws;
  size_t off = 0;
  auto alloc = [&](size_t bytes)->char*{
    char* p = w + off;
    off = (off + bytes + 255) & ~(size_t)255;
    return p;
  };
  int nBlocks = (N + 255) / 256;
  int*   deg     = (int*)  alloc((size_t)N * 4);
  float* inv     = (float*)alloc((size_t)N * 4);
  int*   row_ptr = (int*)  alloc(((size_t)N + 1) * 4);
  int*   cursor  = (int*)  alloc((size_t)N * 4);
  int*   colidx  = (int*)  alloc((size_t)E * 4);
  int*   partial = (int*)  alloc((size_t)nBlocks * 4);
  ushort_t* wt1h = (ushort_t*)alloc((size_t)128 * 256 * 2);
  ushort_t* wt1l = (ushort_t*)alloc((size_t)128 * 256 * 2);
  ushort_t* wt2h = (ushort_t*)alloc((size_t)256 * 256 * 2);
  ushort_t* wt2l = (ushort_t*)alloc((size_t)256 * 256 * 2);
  ushort_t* wt3h = (ushort_t*)alloc((size_t)256 * 128 * 2);
  ushort_t* wt3l = (ushort_t*)alloc((size_t)256 * 128 * 2);
  char* slabA = alloc((size_t)N * 512 * 2);   // 51.2 MB
  char* slabB = alloc((size_t)N * 512 * 2);   // 51.2 MB

  ushort_t* t_pair    = (ushort_t*)slabB;  // [N][256] plane pair
  ushort_t* h1_pair   = (ushort_t*)slabA;  // [N][512] plane pair
  ushort_t* support2b = (ushort_t*)slabB;  // [N][256] bf16
  ushort_t* h2_pair   = (ushort_t*)slabA;  // [N][512] plane pair
  float*    support3  = (float*)slabB;     // [N][128] f32

  hipMemsetAsync(deg, 0, (size_t)N * 4, stream);
  int gE = (E + 255) / 256;
  deg_kernel<<<gE, 256, 0, stream>>>(edges, deg, E);
  scan_part_kernel<<<nBlocks, 256, 0, stream>>>(deg, partial, N);
  scan_top_kernel<<<1, 256, 0, stream>>>(partial, nBlocks);
  scan_fin_kernel<<<nBlocks, 256, 0, stream>>>(deg, partial, row_ptr, cursor, inv, N);
  scatter_kernel<<<gE, 256, 0, stream>>>(edges, cursor, colidx, E);
  sortrows_kernel<<<(N * 64 + 255) / 256, 256, 0, stream>>>(row_ptr, colidx, N);

  wprep_all_kernel<<<512, 256, 0, stream>>>(W1, W2, W3, wt1h, wt1l, wt2h, wt2l, wt3h, wt3l);

  int gm = (N + 127) / 128;
  dim3 g12(gm, 2);
  dim3 g3 (gm, 1);
  int gS64 = (N * 64 + 255) / 256;
  int gS32 = (N * 32 + 255) / 256;

  // layer 1 (reordered): t = A_hat x ; h1 = leaky(t@W1 + mask*b1)  [pair out]
  spmm128_pair_kernel<<<gS32, 256, 0, stream>>>(x, row_ptr, colidx, inv, t_pair, N);
  gemm_mfma_kernel<1><<<g12, 256, 0, stream>>>(t_pair, wt1h, wt1l, b1, inv,
                                               nullptr, h1_pair, N, 128, 256);
  // layer 2: support2 = bf16(h1@W2 + b2) ; h2 = leaky(A_hat support2) [pair out]
  gemm_mfma_kernel<2><<<g12, 256, 0, stream>>>(h1_pair, wt2h, wt2l, b2, nullptr,
                                               nullptr, support2b, N, 256, 256);
  spmm256b_leaky_pair_kernel<<<gS64, 256, 0, stream>>>(support2b, row_ptr, colidx, inv, h2_pair, N);
  // layer 3: support3 = h2@W3 + b3 ; out = normalize(A_hat support3)
  gemm_mfma_kernel<0><<<g3, 256, 0, stream>>>(h2_pair, wt3h, wt3l, b3, nullptr,
                                              support3, nullptr, N, 256, 128);
  spmm_norm_kernel<<<gS32, 256, 0, stream>>>(support3, row_ptr, colidx, inv, (float*)d_out, N);
}

// Round 9
// 369.997 us; speedup vs baseline: 2.6304x; 1.0999x over previous
//
#include <hip/hip_runtime.h>

#define NEG_SLOPE 0.2f

typedef __attribute__((ext_vector_type(8))) short short8;
typedef __attribute__((ext_vector_type(4))) float floatx4;
typedef unsigned short ushort_t;

static __device__ __forceinline__ float leaky(float x){ return x > 0.f ? x : NEG_SLOPE * x; }

static __device__ __forceinline__ unsigned short bf16_rne(float x){
  unsigned u = __float_as_uint(x);
  unsigned r = (u + 0x7fffu + ((u >> 16) & 1u)) >> 16;
  return (unsigned short)r;
}
static __device__ __forceinline__ float bf16_to_f(unsigned short h){
  return __uint_as_float(((unsigned)h) << 16);
}

#define GLOAD_LDS16(g, l) \
  __builtin_amdgcn_global_load_lds((const __attribute__((address_space(1))) unsigned*)(g), \
                                   (__attribute__((address_space(3))) unsigned*)(l), 16, 0, 0)

// ---------------- CSR build ----------------

__global__ void deg_kernel(const int* __restrict__ edges, int* __restrict__ deg, int E){
  int i = blockIdx.x * 256 + threadIdx.x;
  if (i < E) atomicAdd(&deg[edges[2*i + 1]], 1);
}

__global__ __launch_bounds__(256) void scan_part_kernel(const int* __restrict__ deg,
                                                        int* __restrict__ partial, int n){
  int i = blockIdx.x * 256 + threadIdx.x;
  int v = (i < n) ? deg[i] : 0;
  #pragma unroll
  for (int o = 32; o > 0; o >>= 1) v += __shfl_xor(v, o);
  __shared__ int ws[4];
  if ((threadIdx.x & 63) == 0) ws[threadIdx.x >> 6] = v;
  __syncthreads();
  if (threadIdx.x == 0) partial[blockIdx.x] = ws[0] + ws[1] + ws[2] + ws[3];
}

__global__ __launch_bounds__(256) void scan_top_kernel(int* __restrict__ partial, int nb){
  int t = threadIdx.x;
  int lane = t & 63, w = t >> 6;
  int v = (t < nb) ? partial[t] : 0;
  int sc = v;
  #pragma unroll
  for (int o = 1; o < 64; o <<= 1){
    int x = __shfl_up(sc, o);
    if (lane >= o) sc += x;
  }
  __shared__ int wt[4];
  if (lane == 63) wt[w] = sc;
  __syncthreads();
  int base = 0;
  for (int j = 0; j < w; j++) base += wt[j];
  if (t < nb) partial[t] = base + sc - v;
}

__global__ __launch_bounds__(256) void scan_fin_kernel(const int* __restrict__ deg,
    const int* __restrict__ partial, int* __restrict__ row_ptr, int* __restrict__ cursor,
    float* __restrict__ inv, int n){
  int b = blockIdx.x, t = threadIdx.x;
  int i = b * 256 + t;
  int lane = t & 63, w = t >> 6;
  int v = (i < n) ? deg[i] : 0;
  int sc = v;
  #pragma unroll
  for (int o = 1; o < 64; o <<= 1){
    int x = __shfl_up(sc, o);
    if (lane >= o) sc += x;
  }
  __shared__ int wt[4];
  if (lane == 63) wt[w] = sc;
  __syncthreads();
  int base = partial[b];
  for (int j = 0; j < w; j++) base += wt[j];
  int excl = base + sc - v;
  if (i < n){
    row_ptr[i] = excl;
    cursor[i]  = excl;
    inv[i] = (v > 0) ? 1.0f / (float)v : 0.0f;
    if (i == n - 1) row_ptr[n] = excl + v;
  }
}

__global__ void scatter_kernel(const int* __restrict__ edges, int* __restrict__ cursor,
                               int* __restrict__ col, int E){
  int i = blockIdx.x * 256 + threadIdx.x;
  if (i < E){
    int s = edges[2*i], d = edges[2*i + 1];
    int p = atomicAdd(&cursor[d], 1);
    col[p] = s;
  }
}

// Deterministic col order per row (harness re-validates after replays; f32 sum
// order must be call-invariant). Wave-bitonic sort, all in registers.
__global__ __launch_bounds__(256) void sortrows_kernel(const int* __restrict__ row_ptr,
                                                       int* __restrict__ col, int n){
  int gw = (blockIdx.x * 256 + threadIdx.x) >> 6;
  int lane = threadIdx.x & 63;
  if (gw >= n) return;
  int s = row_ptr[gw], e = row_ptr[gw + 1];
  int len = e - s;
  if (len <= 1) return;
  if (len <= 64){
    int v = (lane < len) ? col[s + lane] : 0x7fffffff;
    #pragma unroll
    for (int k = 2; k <= 64; k <<= 1){
      #pragma unroll
      for (int j = k >> 1; j > 0; j >>= 1){
        int o = __shfl_xor(v, j);
        bool dirUp = ((lane & k) == 0);
        bool takeMin = (((lane & j) == 0) == dirUp);
        v = takeMin ? min(v, o) : max(v, o);
      }
    }
    if (lane < len) col[s + lane] = v;
  } else if (lane == 0){
    for (int i = s + 1; i < e; ++i){
      int v = col[i];
      int j = i - 1;
      while (j >= s && col[j] > v){ col[j + 1] = col[j]; --j; }
      col[j + 1] = v;
    }
  }
}

// ---------------- x -> bf16 ----------------

__global__ __launch_bounds__(256) void xprep_kernel(const float* __restrict__ x,
    ushort_t* __restrict__ xb, int total){   // total = n*128, multiple of 8
  int i = (blockIdx.x * 256 + threadIdx.x) * 8;
  if (i >= total) return;
  float4 a = *(const float4*)(x + i);
  float4 b = *(const float4*)(x + i + 4);
  short8 o;
  o[0] = (short)bf16_rne(a.x); o[1] = (short)bf16_rne(a.y);
  o[2] = (short)bf16_rne(a.z); o[3] = (short)bf16_rne(a.w);
  o[4] = (short)bf16_rne(b.x); o[5] = (short)bf16_rne(b.y);
  o[6] = (short)bf16_rne(b.z); o[7] = (short)bf16_rne(b.w);
  *(short8*)(xb + i) = o;
}

// ---------------- W prep (all 3 weights, one launch) ----------------
// W [K][N] f32 -> transposed bf16 hi/lo planes [N][K].

__global__ void wprep_all_kernel(const float* __restrict__ W1, const float* __restrict__ W2,
    const float* __restrict__ W3, ushort_t* __restrict__ h1, ushort_t* __restrict__ l1,
    ushort_t* __restrict__ h2, ushort_t* __restrict__ l2,
    ushort_t* __restrict__ h3, ushort_t* __restrict__ l3){
  int i = blockIdx.x * 256 + threadIdx.x;
  const float* W; ushort_t* hp; ushort_t* lp; int K, N, idx;
  if (i < 32768)      { W = W1; hp = h1; lp = l1; K = 128; N = 256; idx = i; }
  else if (i < 98304) { W = W2; hp = h2; lp = l2; K = 256; N = 256; idx = i - 32768; }
  else if (i < 131072){ W = W3; hp = h3; lp = l3; K = 256; N = 128; idx = i - 98304; }
  else return;
  int k = idx / N, n = idx - k * N;
  float a = W[idx];
  ushort_t h = bf16_rne(a);
  hp[(size_t)n * K + k] = h;
  lp[(size_t)n * K + k] = bf16_rne(a - bf16_to_f(h));
}

// ---------------- MFMA GEMM ----------------
// A: [M][K] bf16 (single plane). W split hi/lo -> 2-term: Ah*Wh + Ah*Wl.
// 128x128 tile, 4 waves 2x2, outer K-step 64 (two 32-k substeps per stage).
// LDS: sA 128 rows x 128B (8 chunks = 64 k), sB[2] each 128 rows x 128B
// ([Wh 4ch | Wl 4ch] per 32-k substep). Logical chunk j of row r at byte
// (j*16)^((r&7)<<4); staged via global_load_lds with linear LDS dest +
// inverse-swizzled global source.
// MODE: 0 = f32 out + bias; 1 = bf16 out, leaky, bias masked by inv>0;
//       2 = bf16 out + bias.

template<int MODE>
__global__ __launch_bounds__(256) void gemm_mfma_kernel(
    const ushort_t* __restrict__ A,
    const ushort_t* __restrict__ Bt_hi, const ushort_t* __restrict__ Bt_lo,
    const float* __restrict__ bias, const float* __restrict__ invv,
    float* __restrict__ Cf, ushort_t* __restrict__ Cp,
    int M, int K, int N){
  __shared__ ushort_t sA[128 * 64];      // 16 KB
  __shared__ ushort_t sB[2][128 * 64];   // 32 KB
  const int tid  = threadIdx.x;
  const int lane = tid & 63;
  const int wid  = tid >> 6;
  const int wrow = wid >> 1;
  const int wcol = wid & 1;
  const int br = blockIdx.x * 128;
  const int bc = blockIdx.y * 128;

  floatx4 acc[4][4];
  #pragma unroll
  for (int i = 0; i < 4; i++)
    #pragma unroll
    for (int j = 0; j < 4; j++) acc[i][j] = (floatx4){0.f, 0.f, 0.f, 0.f};

  char* pa = (char*)sA;
  const int g16 = (lane >> 4) << 4;
  const int r_st = tid >> 3;
  const int c_st = tid & 7;

  for (int k0 = 0; k0 < K; k0 += 64){
    // ---- stage A (64 k) + B (2 substeps x [hi|lo]) ----
    #pragma unroll
    for (int q = 0; q < 4; q++){
      int r  = q * 32 + r_st;
      int sc = c_st ^ (r & 7);                 // inverse-swizzled logical chunk
      {
        int grow = br + r;
        if (grow < M){
          const ushort_t* src = A + (size_t)grow * K + k0 + sc * 8;
          GLOAD_LDS16(src, pa + q * 4096 + wid * 1024);
        }
      }
      {
        int gcol = bc + r;
        const ushort_t* b0 = (sc < 4) ? (Bt_hi + (size_t)gcol * K + k0 + sc * 8)
                                      : (Bt_lo + (size_t)gcol * K + k0 + (sc - 4) * 8);
        GLOAD_LDS16(b0, ((char*)sB[0]) + q * 4096 + wid * 1024);
        const ushort_t* b1 = (sc < 4) ? (Bt_hi + (size_t)gcol * K + k0 + 32 + sc * 8)
                                      : (Bt_lo + (size_t)gcol * K + k0 + 32 + (sc - 4) * 8);
        GLOAD_LDS16(b1, ((char*)sB[1]) + q * 4096 + wid * 1024);
      }
    }
    __syncthreads();
    #pragma unroll
    for (int sub = 0; sub < 2; sub++){
      const char* pb = (const char*)sB[sub];
      short8 bh[4], bl[4];
      #pragma unroll
      for (int nf = 0; nf < 4; nf++){
        int coll = wcol * 64 + nf * 16 + (lane & 15);
        unsigned sw = (coll & 7) << 4;
        const char* pr = pb + coll * 128;
        bh[nf] = *(const short8*)(pr + ((g16) ^ sw));
        bl[nf] = *(const short8*)(pr + ((64 + g16) ^ sw));
      }
      #pragma unroll
      for (int mf = 0; mf < 4; mf++){
        int rowl = wrow * 64 + mf * 16 + (lane & 15);
        unsigned sw = (rowl & 7) << 4;
        short8 ah = *(const short8*)(pa + rowl * 128 + ((sub * 64 + g16) ^ sw));
        #pragma unroll
        for (int nf = 0; nf < 4; nf++){
          acc[mf][nf] = __builtin_amdgcn_mfma_f32_16x16x32_bf16(ah, bh[nf], acc[mf][nf], 0, 0, 0);
          acc[mf][nf] = __builtin_amdgcn_mfma_f32_16x16x32_bf16(ah, bl[nf], acc[mf][nf], 0, 0, 0);
        }
      }
    }
    __syncthreads();
  }

  const int r0 = br + wrow * 64;
  const int c0 = bc + wcol * 64;
  #pragma unroll
  for (int nf = 0; nf < 4; nf++){
    int col = c0 + nf * 16 + (lane & 15);
    float bv = bias[col];
    #pragma unroll
    for (int mf = 0; mf < 4; mf++){
      int rbase = r0 + mf * 16 + ((lane >> 4) << 2);
      #pragma unroll
      for (int j = 0; j < 4; j++){
        int r = rbase + j;
        if (r >= M) continue;
        if (MODE == 1){
          float m = (invv[r] > 0.f) ? 1.f : 0.f;
          Cp[(size_t)r * N + col] = bf16_rne(leaky(acc[mf][nf][j] + m * bv));
        } else if (MODE == 2){
          Cp[(size_t)r * N + col] = bf16_rne(acc[mf][nf][j] + bv);
        } else {
          Cf[(size_t)r * N + col] = acc[mf][nf][j] + bv;
        }
      }
    }
  }
}

// ---------------- SpMM kernels (CSR gather) ----------------

// xb (bf16 [n][128]) -> t (bf16 [n][128]); t = inv * sum xb[src]
// 2 rows per wave: 32 lanes/row, ushort4 (8B)/lane, unroll-4, f32 accum.
__global__ __launch_bounds__(256) void spmm128b_kernel(const ushort_t* __restrict__ xb,
    const int* __restrict__ row_ptr, const int* __restrict__ col,
    const float* __restrict__ inv, ushort_t* __restrict__ out, int n){
  int gw = (blockIdx.x * 256 + threadIdx.x) >> 5;
  int lane = threadIdx.x & 31;
  if (gw >= n) return;
  int s = row_ptr[gw], e = row_ptr[gw + 1];
  float ir = inv[gw];
  int off = lane * 4;
  float4 a0 = make_float4(0.f,0.f,0.f,0.f), a1 = make_float4(0.f,0.f,0.f,0.f);
  float4 a2 = make_float4(0.f,0.f,0.f,0.f), a3 = make_float4(0.f,0.f,0.f,0.f);
  int i = s;
  for (; i + 3 < e; i += 4){
    int c0 = col[i], c1 = col[i+1], c2 = col[i+2], c3 = col[i+3];
    ushort4 u0 = *(const ushort4*)(xb + (size_t)c0 * 128 + off);
    ushort4 u1 = *(const ushort4*)(xb + (size_t)c1 * 128 + off);
    ushort4 u2 = *(const ushort4*)(xb + (size_t)c2 * 128 + off);
    ushort4 u3 = *(const ushort4*)(xb + (size_t)c3 * 128 + off);
    a0.x += bf16_to_f(u0.x); a0.y += bf16_to_f(u0.y); a0.z += bf16_to_f(u0.z); a0.w += bf16_to_f(u0.w);
    a1.x += bf16_to_f(u1.x); a1.y += bf16_to_f(u1.y); a1.z += bf16_to_f(u1.z); a1.w += bf16_to_f(u1.w);
    a2.x += bf16_to_f(u2.x); a2.y += bf16_to_f(u2.y); a2.z += bf16_to_f(u2.z); a2.w += bf16_to_f(u2.w);
    a3.x += bf16_to_f(u3.x); a3.y += bf16_to_f(u3.y); a3.z += bf16_to_f(u3.z); a3.w += bf16_to_f(u3.w);
  }
  for (; i < e; ++i){
    int c0 = col[i];
    ushort4 u0 = *(const ushort4*)(xb + (size_t)c0 * 128 + off);
    a0.x += bf16_to_f(u0.x); a0.y += bf16_to_f(u0.y); a0.z += bf16_to_f(u0.z); a0.w += bf16_to_f(u0.w);
  }
  ushort4 ov;
  ov.x = bf16_rne(((a0.x + a1.x) + (a2.x + a3.x)) * ir);
  ov.y = bf16_rne(((a0.y + a1.y) + (a2.y + a3.y)) * ir);
  ov.z = bf16_rne(((a0.z + a1.z) + (a2.z + a3.z)) * ir);
  ov.w = bf16_rne(((a0.w + a1.w) + (a2.w + a3.w)) * ir);
  *(ushort4*)(out + (size_t)gw * 128 + off) = ov;
}

// support2 (bf16 [n][256]) -> h2 (bf16 [n][256]); h = leaky(inv * sum)
// 1 row per wave: 64 lanes, ushort4/lane, unroll-4, f32 accum.
__global__ __launch_bounds__(256) void spmm256b_leaky_kernel(const ushort_t* __restrict__ sup,
    const int* __restrict__ row_ptr, const int* __restrict__ col,
    const float* __restrict__ inv, ushort_t* __restrict__ out, int n){
  int gw = (blockIdx.x * 256 + threadIdx.x) >> 6;
  int lane = threadIdx.x & 63;
  if (gw >= n) return;
  int s = row_ptr[gw], e = row_ptr[gw + 1];
  float ir = inv[gw];
  int off = lane * 4;
  float4 a0 = make_float4(0.f,0.f,0.f,0.f), a1 = make_float4(0.f,0.f,0.f,0.f);
  float4 a2 = make_float4(0.f,0.f,0.f,0.f), a3 = make_float4(0.f,0.f,0.f,0.f);
  int i = s;
  for (; i + 3 < e; i += 4){
    int c0 = col[i], c1 = col[i+1], c2 = col[i+2], c3 = col[i+3];
    ushort4 u0 = *(const ushort4*)(sup + (size_t)c0 * 256 + off);
    ushort4 u1 = *(const ushort4*)(sup + (size_t)c1 * 256 + off);
    ushort4 u2 = *(const ushort4*)(sup + (size_t)c2 * 256 + off);
    ushort4 u3 = *(const ushort4*)(sup + (size_t)c3 * 256 + off);
    a0.x += bf16_to_f(u0.x); a0.y += bf16_to_f(u0.y); a0.z += bf16_to_f(u0.z); a0.w += bf16_to_f(u0.w);
    a1.x += bf16_to_f(u1.x); a1.y += bf16_to_f(u1.y); a1.z += bf16_to_f(u1.z); a1.w += bf16_to_f(u1.w);
    a2.x += bf16_to_f(u2.x); a2.y += bf16_to_f(u2.y); a2.z += bf16_to_f(u2.z); a2.w += bf16_to_f(u2.w);
    a3.x += bf16_to_f(u3.x); a3.y += bf16_to_f(u3.y); a3.z += bf16_to_f(u3.z); a3.w += bf16_to_f(u3.w);
  }
  for (; i < e; ++i){
    int c0 = col[i];
    ushort4 u0 = *(const ushort4*)(sup + (size_t)c0 * 256 + off);
    a0.x += bf16_to_f(u0.x); a0.y += bf16_to_f(u0.y); a0.z += bf16_to_f(u0.z); a0.w += bf16_to_f(u0.w);
  }
  ushort4 ov;
  ov.x = bf16_rne(leaky(((a0.x + a1.x) + (a2.x + a3.x)) * ir));
  ov.y = bf16_rne(leaky(((a0.y + a1.y) + (a2.y + a3.y)) * ir));
  ov.z = bf16_rne(leaky(((a0.z + a1.z) + (a2.z + a3.z)) * ir));
  ov.w = bf16_rne(leaky(((a0.w + a1.w) + (a2.w + a3.w)) * ir));
  *(ushort4*)(out + (size_t)gw * 256 + off) = ov;
}

// support3 (f32 [n][128]) -> out f32 [n][128]; inv-scale + L2 row-normalize
__global__ __launch_bounds__(256) void spmm_norm_kernel(const float* __restrict__ sup,
    const int* __restrict__ row_ptr, const int* __restrict__ col,
    const float* __restrict__ inv, float* __restrict__ out, int n){
  int gw = (blockIdx.x * 256 + threadIdx.x) >> 5;
  int lane = threadIdx.x & 31;
  if (gw >= n) return;
  int s = row_ptr[gw], e = row_ptr[gw + 1];
  float ir = inv[gw];
  int off = lane * 4;
  float4 a0 = make_float4(0.f,0.f,0.f,0.f), a1 = make_float4(0.f,0.f,0.f,0.f);
  float4 a2 = make_float4(0.f,0.f,0.f,0.f), a3 = make_float4(0.f,0.f,0.f,0.f);
  int i = s;
  for (; i + 3 < e; i += 4){
    int c0 = col[i], c1 = col[i+1], c2 = col[i+2], c3 = col[i+3];
    float4 v0 = *(const float4*)(sup + (size_t)c0 * 128 + off);
    float4 v1 = *(const float4*)(sup + (size_t)c1 * 128 + off);
    float4 v2 = *(const float4*)(sup + (size_t)c2 * 128 + off);
    float4 v3 = *(const float4*)(sup + (size_t)c3 * 128 + off);
    a0.x += v0.x; a0.y += v0.y; a0.z += v0.z; a0.w += v0.w;
    a1.x += v1.x; a1.y += v1.y; a1.z += v1.z; a1.w += v1.w;
    a2.x += v2.x; a2.y += v2.y; a2.z += v2.z; a2.w += v2.w;
    a3.x += v3.x; a3.y += v3.y; a3.z += v3.z; a3.w += v3.w;
  }
  for (; i < e; ++i){
    int c0 = col[i];
    float4 v0 = *(const float4*)(sup + (size_t)c0 * 128 + off);
    a0.x += v0.x; a0.y += v0.y; a0.z += v0.z; a0.w += v0.w;
  }
  float v0 = ((a0.x + a1.x) + (a2.x + a3.x)) * ir;
  float v1 = ((a0.y + a1.y) + (a2.y + a3.y)) * ir;
  float v2 = ((a0.z + a1.z) + (a2.z + a3.z)) * ir;
  float v3 = ((a0.w + a1.w) + (a2.w + a3.w)) * ir;
  float ss = v0*v0 + v1*v1 + v2*v2 + v3*v3;
  #pragma unroll
  for (int o = 16; o > 0; o >>= 1) ss += __shfl_xor(ss, o);
  float scale = 1.0f / fmaxf(sqrtf(ss), 1e-12f);
  float4 ov;
  ov.x = v0 * scale; ov.y = v1 * scale; ov.z = v2 * scale; ov.w = v3 * scale;
  *(float4*)(out + (size_t)gw * 128 + off) = ov;
}

// ---------------- launch ----------------

extern "C" void kernel_launch(void* const* d_in, const int* in_sizes, int n_in,
                              void* d_out, int out_size, void* d_ws, size_t ws_size,
                              hipStream_t stream){
  const float* x  = (const float*)d_in[0];
  const float* W1 = (const float*)d_in[1];
  const float* b1 = (const float*)d_in[2];
  const float* W2 = (const float*)d_in[3];
  const float* b2 = (const float*)d_in[4];
  const float* W3 = (const float*)d_in[5];
  const float* b3 = (const float*)d_in[6];
  const int* edges = (const int*)d_in[7];
  int N = in_sizes[0] / 128;
  int E = in_sizes[7] / 2;

  char* w = (char*)d_ws;
  size_t off = 0;
  auto alloc = [&](size_t bytes)->char*{
    char* p = w + off;
    off = (off + bytes + 255) & ~(size_t)255;
    return p;
  };
  int nBlocks = (N + 255) / 256;
  int*   deg     = (int*)  alloc((size_t)N * 4);
  float* inv     = (float*)alloc((size_t)N * 4);
  int*   row_ptr = (int*)  alloc(((size_t)N + 1) * 4);
  int*   cursor  = (int*)  alloc((size_t)N * 4);
  int*   colidx  = (int*)  alloc((size_t)E * 4);
  int*   partial = (int*)  alloc((size_t)nBlocks * 4);
  ushort_t* wt1h = (ushort_t*)alloc((size_t)128 * 256 * 2);
  ushort_t* wt1l = (ushort_t*)alloc((size_t)128 * 256 * 2);
  ushort_t* wt2h = (ushort_t*)alloc((size_t)256 * 256 * 2);
  ushort_t* wt2l = (ushort_t*)alloc((size_t)256 * 256 * 2);
  ushort_t* wt3h = (ushort_t*)alloc((size_t)256 * 128 * 2);
  ushort_t* wt3l = (ushort_t*)alloc((size_t)256 * 128 * 2);
  char* slabA = alloc((size_t)N * 512 * 2);   // 51.2 MB
  char* slabB = alloc((size_t)N * 512 * 2);   // 51.2 MB

  ushort_t* xb        = (ushort_t*)slabA;                       // [N][128] bf16
  ushort_t* t_buf     = (ushort_t*)(slabA + (size_t)N * 256);   // [N][128] bf16
  ushort_t* h1_buf    = (ushort_t*)slabB;                       // [N][256] bf16
  ushort_t* s2_buf    = (ushort_t*)(slabA + (size_t)N * 512);   // [N][256] bf16
  ushort_t* h2_buf    = (ushort_t*)(slabB + (size_t)N * 512);   // [N][256] bf16
  float*    support3  = (float*)slabA;                          // [N][128] f32 (xb/t dead)

  hipMemsetAsync(deg, 0, (size_t)N * 4, stream);
  int gE = (E + 255) / 256;
  deg_kernel<<<gE, 256, 0, stream>>>(edges, deg, E);
  scan_part_kernel<<<nBlocks, 256, 0, stream>>>(deg, partial, N);
  scan_top_kernel<<<1, 256, 0, stream>>>(partial, nBlocks);
  scan_fin_kernel<<<nBlocks, 256, 0, stream>>>(deg, partial, row_ptr, cursor, inv, N);
  scatter_kernel<<<gE, 256, 0, stream>>>(edges, cursor, colidx, E);
  sortrows_kernel<<<(N * 64 + 255) / 256, 256, 0, stream>>>(row_ptr, colidx, N);

  wprep_all_kernel<<<512, 256, 0, stream>>>(W1, W2, W3, wt1h, wt1l, wt2h, wt2l, wt3h, wt3l);
  xprep_kernel<<<(N * 128 / 8 + 255) / 256, 256, 0, stream>>>(x, xb, N * 128);

  int gm = (N + 127) / 128;
  dim3 g12(gm, 2);
  dim3 g3 (gm, 1);
  int gS64 = (N * 64 + 255) / 256;
  int gS32 = (N * 32 + 255) / 256;

  // layer 1 (reordered): t = A_hat xb ; h1 = bf16(leaky(t@W1 + mask*b1))
  spmm128b_kernel<<<gS32, 256, 0, stream>>>(xb, row_ptr, colidx, inv, t_buf, N);
  gemm_mfma_kernel<1><<<g12, 256, 0, stream>>>(t_buf, wt1h, wt1l, b1, inv,
                                               nullptr, h1_buf, N, 128, 256);
  // layer 2: s2 = bf16(h1@W2 + b2) ; h2 = bf16(leaky(A_hat s2))
  gemm_mfma_kernel<2><<<g12, 256, 0, stream>>>(h1_buf, wt2h, wt2l, b2, nullptr,
                                               nullptr, s2_buf, N, 256, 256);
  spmm256b_leaky_kernel<<<gS64, 256, 0, stream>>>(s2_buf, row_ptr, colidx, inv, h2_buf, N);
  // layer 3: support3 = h2@W3 + b3 ; out = normalize(A_hat support3)
  gemm_mfma_kernel<0><<<g3, 256, 0, stream>>>(h2_buf, wt3h, wt3l, b3, nullptr,
                                              support3, nullptr, N, 256, 128);
  spmm_norm_kernel<<<gS32, 256, 0, stream>>>(support3, row_ptr, colidx, inv, (float*)d_out, N);
}

// Round 10
// 360.523 us; speedup vs baseline: 2.6995x; 1.0263x over previous
//
#include <hip/hip_runtime.h>

#define NEG_SLOPE 0.2f

typedef __attribute__((ext_vector_type(8))) short short8;
typedef __attribute__((ext_vector_type(4))) float floatx4;
typedef unsigned short ushort_t;

static __device__ __forceinline__ float leaky(float x){ return x > 0.f ? x : NEG_SLOPE * x; }

static __device__ __forceinline__ unsigned short bf16_rne(float x){
  unsigned u = __float_as_uint(x);
  unsigned r = (u + 0x7fffu + ((u >> 16) & 1u)) >> 16;
  return (unsigned short)r;
}
static __device__ __forceinline__ float bf16_to_f(unsigned short h){
  return __uint_as_float(((unsigned)h) << 16);
}

#define GLOAD_LDS16(g, l) \
  __builtin_amdgcn_global_load_lds((const __attribute__((address_space(1))) unsigned*)(g), \
                                   (__attribute__((address_space(3))) unsigned*)(l), 16, 0, 0)

// ---------------- CSR build ----------------

__global__ void deg_kernel(const int* __restrict__ edges, int* __restrict__ deg, int E){
  int i = blockIdx.x * 256 + threadIdx.x;
  if (i < E) atomicAdd(&deg[edges[2*i + 1]], 1);
}

__global__ __launch_bounds__(256) void scan_part_kernel(const int* __restrict__ deg,
                                                        int* __restrict__ partial, int n){
  int i = blockIdx.x * 256 + threadIdx.x;
  int v = (i < n) ? deg[i] : 0;
  #pragma unroll
  for (int o = 32; o > 0; o >>= 1) v += __shfl_xor(v, o);
  __shared__ int ws[4];
  if ((threadIdx.x & 63) == 0) ws[threadIdx.x >> 6] = v;
  __syncthreads();
  if (threadIdx.x == 0) partial[blockIdx.x] = ws[0] + ws[1] + ws[2] + ws[3];
}

__global__ __launch_bounds__(256) void scan_top_kernel(int* __restrict__ partial, int nb){
  int t = threadIdx.x;
  int lane = t & 63, w = t >> 6;
  int v = (t < nb) ? partial[t] : 0;
  int sc = v;
  #pragma unroll
  for (int o = 1; o < 64; o <<= 1){
    int x = __shfl_up(sc, o);
    if (lane >= o) sc += x;
  }
  __shared__ int wt[4];
  if (lane == 63) wt[w] = sc;
  __syncthreads();
  int base = 0;
  for (int j = 0; j < w; j++) base += wt[j];
  if (t < nb) partial[t] = base + sc - v;
}

__global__ __launch_bounds__(256) void scan_fin_kernel(const int* __restrict__ deg,
    const int* __restrict__ partial, int* __restrict__ row_ptr, int* __restrict__ cursor,
    float* __restrict__ inv, int n){
  int b = blockIdx.x, t = threadIdx.x;
  int i = b * 256 + t;
  int lane = t & 63, w = t >> 6;
  int v = (i < n) ? deg[i] : 0;
  int sc = v;
  #pragma unroll
  for (int o = 1; o < 64; o <<= 1){
    int x = __shfl_up(sc, o);
    if (lane >= o) sc += x;
  }
  __shared__ int wt[4];
  if (lane == 63) wt[w] = sc;
  __syncthreads();
  int base = partial[b];
  for (int j = 0; j < w; j++) base += wt[j];
  int excl = base + sc - v;
  if (i < n){
    row_ptr[i] = excl;
    cursor[i]  = excl;
    inv[i] = (v > 0) ? 1.0f / (float)v : 0.0f;
    if (i == n - 1) row_ptr[n] = excl + v;
  }
}

__global__ void scatter_kernel(const int* __restrict__ edges, int* __restrict__ cursor,
                               int* __restrict__ col, int E){
  int i = blockIdx.x * 256 + threadIdx.x;
  if (i < E){
    int s = edges[2*i], d = edges[2*i + 1];
    int p = atomicAdd(&cursor[d], 1);
    col[p] = s;
  }
}

// Deterministic col order per row (harness re-validates after replays; f32 sum
// order must be call-invariant). Wave-bitonic sort, all in registers.
__global__ __launch_bounds__(256) void sortrows_kernel(const int* __restrict__ row_ptr,
                                                       int* __restrict__ col, int n){
  int gw = (blockIdx.x * 256 + threadIdx.x) >> 6;
  int lane = threadIdx.x & 63;
  if (gw >= n) return;
  int s = row_ptr[gw], e = row_ptr[gw + 1];
  int len = e - s;
  if (len <= 1) return;
  if (len <= 64){
    int v = (lane < len) ? col[s + lane] : 0x7fffffff;
    #pragma unroll
    for (int k = 2; k <= 64; k <<= 1){
      #pragma unroll
      for (int j = k >> 1; j > 0; j >>= 1){
        int o = __shfl_xor(v, j);
        bool dirUp = ((lane & k) == 0);
        bool takeMin = (((lane & j) == 0) == dirUp);
        v = takeMin ? min(v, o) : max(v, o);
      }
    }
    if (lane < len) col[s + lane] = v;
  } else if (lane == 0){
    for (int i = s + 1; i < e; ++i){
      int v = col[i];
      int j = i - 1;
      while (j >= s && col[j] > v){ col[j + 1] = col[j]; --j; }
      col[j + 1] = v;
    }
  }
}

// ---------------- x -> bf16 ----------------

__global__ __launch_bounds__(256) void xprep_kernel(const float* __restrict__ x,
    ushort_t* __restrict__ xb, int total){
  int i = (blockIdx.x * 256 + threadIdx.x) * 8;
  if (i >= total) return;
  float4 a = *(const float4*)(x + i);
  float4 b = *(const float4*)(x + i + 4);
  short8 o;
  o[0] = (short)bf16_rne(a.x); o[1] = (short)bf16_rne(a.y);
  o[2] = (short)bf16_rne(a.z); o[3] = (short)bf16_rne(a.w);
  o[4] = (short)bf16_rne(b.x); o[5] = (short)bf16_rne(b.y);
  o[6] = (short)bf16_rne(b.z); o[7] = (short)bf16_rne(b.w);
  *(short8*)(xb + i) = o;
}

// ---------------- W prep (all 3 weights, one launch) ----------------

__global__ void wprep_all_kernel(const float* __restrict__ W1, const float* __restrict__ W2,
    const float* __restrict__ W3, ushort_t* __restrict__ h1, ushort_t* __restrict__ l1,
    ushort_t* __restrict__ h2, ushort_t* __restrict__ l2,
    ushort_t* __restrict__ h3, ushort_t* __restrict__ l3){
  int i = blockIdx.x * 256 + threadIdx.x;
  const float* W; ushort_t* hp; ushort_t* lp; int K, N, idx;
  if (i < 32768)      { W = W1; hp = h1; lp = l1; K = 128; N = 256; idx = i; }
  else if (i < 98304) { W = W2; hp = h2; lp = l2; K = 256; N = 256; idx = i - 32768; }
  else if (i < 131072){ W = W3; hp = h3; lp = l3; K = 256; N = 128; idx = i - 98304; }
  else return;
  int k = idx / N, n = idx - k * N;
  float a = W[idx];
  ushort_t h = bf16_rne(a);
  hp[(size_t)n * K + k] = h;
  lp[(size_t)n * K + k] = bf16_rne(a - bf16_to_f(h));
}

// ---------------- MFMA GEMM ----------------
// A: [M][K] bf16. W split hi/lo -> 2-term: Ah*Wh + Ah*Wl, f32 accum.
// 128x128 tile, 4 waves 2x2, BK=32, LDS DOUBLE-BUFFERED, one barrier/K-step
// (STAGE(t+1) -> COMPUTE(t) -> __syncthreads: loads fly under compute).
// K-major granule-plane LDS (conflict-free, no swizzle):
//   A buf: [4 granule][128 row] x 16B (8KB); granule g holds k = g*8..g*8+7.
//   B buf: [8 granule][128 col] x 16B (16KB); planes 0-3 = Wh, 4-7 = Wl.
// Staged via global_load_lds (linear dest: chunk c -> plane c>>7, row c&127).
// MODE: 1 = bf16 out, leaky, bias masked by inv>0; 2 = bf16 out + bias.

template<int MODE>
__global__ __launch_bounds__(256) void gemm_mfma_kernel(
    const ushort_t* __restrict__ A,
    const ushort_t* __restrict__ Bt_hi, const ushort_t* __restrict__ Bt_lo,
    const float* __restrict__ bias, const float* __restrict__ invv,
    ushort_t* __restrict__ Cp,
    int M, int K, int N){
  __shared__ ushort_t lds[2][12288];   // per buf: A 4096 u16 + B 8192 u16 = 24KB
  const int tid  = threadIdx.x;
  const int lane = tid & 63;
  const int wid  = tid >> 6;
  const int wrow = wid >> 1;
  const int wcol = wid & 1;
  const int br = blockIdx.x * 128;
  const int bc = blockIdx.y * 128;

  floatx4 acc[4][4];
  #pragma unroll
  for (int i = 0; i < 4; i++)
    #pragma unroll
    for (int j = 0; j < 4; j++) acc[i][j] = (floatx4){0.f, 0.f, 0.f, 0.f};

  auto STAGE = [&](int b, int k0){
    char* bufA = (char*)&lds[b][0];
    char* bufB = (char*)&lds[b][4096];
    #pragma unroll
    for (int q = 0; q < 2; q++){
      int c = q * 256 + tid;
      int g = c >> 7, r = c & 127;
      int grow = br + r;
      if (grow < M)
        GLOAD_LDS16(A + (size_t)grow * K + k0 + g * 8,
                    bufA + (q * 256 + wid * 64) * 16);
    }
    #pragma unroll
    for (int q = 0; q < 4; q++){
      int c = q * 256 + tid;
      int g = c >> 7, colc = c & 127;
      int gcol = bc + colc;
      const ushort_t* src = (g < 4) ? (Bt_hi + (size_t)gcol * K + k0 + g * 8)
                                    : (Bt_lo + (size_t)gcol * K + k0 + (g - 4) * 8);
      GLOAD_LDS16(src, bufB + (q * 256 + wid * 64) * 16);
    }
  };

  auto COMPUTE = [&](int b){
    const ushort_t* bufA = &lds[b][0];
    const ushort_t* bufB = &lds[b][4096];
    const int gsel = (lane >> 4) * 1024;   // granule plane, ushort units
    short8 bh[4], bl[4];
    #pragma unroll
    for (int nf = 0; nf < 4; nf++){
      int off = gsel + (wcol * 64 + nf * 16 + (lane & 15)) * 8;
      bh[nf] = *(const short8*)(bufB + off);
      bl[nf] = *(const short8*)(bufB + 4096 + off);
    }
    #pragma unroll
    for (int mf = 0; mf < 4; mf++){
      short8 ah = *(const short8*)(bufA + gsel + (wrow * 64 + mf * 16 + (lane & 15)) * 8);
      #pragma unroll
      for (int nf = 0; nf < 4; nf++){
        acc[mf][nf] = __builtin_amdgcn_mfma_f32_16x16x32_bf16(ah, bh[nf], acc[mf][nf], 0, 0, 0);
        acc[mf][nf] = __builtin_amdgcn_mfma_f32_16x16x32_bf16(ah, bl[nf], acc[mf][nf], 0, 0, 0);
      }
    }
  };

  const int nt = K >> 5;
  STAGE(0, 0);
  __syncthreads();
  for (int t = 0; t < nt; ++t){
    if (t + 1 < nt) STAGE((t + 1) & 1, (t + 1) << 5);
    COMPUTE(t & 1);
    __syncthreads();
  }

  const int r0 = br + wrow * 64;
  const int c0 = bc + wcol * 64;
  #pragma unroll
  for (int nf = 0; nf < 4; nf++){
    int col = c0 + nf * 16 + (lane & 15);
    float bv = bias[col];
    #pragma unroll
    for (int mf = 0; mf < 4; mf++){
      int rbase = r0 + mf * 16 + ((lane >> 4) << 2);
      #pragma unroll
      for (int j = 0; j < 4; j++){
        int r = rbase + j;
        if (r >= M) continue;
        if (MODE == 1){
          float m = (invv[r] > 0.f) ? 1.f : 0.f;
          Cp[(size_t)r * N + col] = bf16_rne(leaky(acc[mf][nf][j] + m * bv));
        } else {
          Cp[(size_t)r * N + col] = bf16_rne(acc[mf][nf][j] + bv);
        }
      }
    }
  }
}

// ---------------- SpMM kernels (CSR gather, bf16 src, f32 accum) ----------------

// xb (bf16 [n][128]) -> t (bf16 [n][128]); t = inv * sum
__global__ __launch_bounds__(256) void spmm128b_kernel(const ushort_t* __restrict__ xb,
    const int* __restrict__ row_ptr, const int* __restrict__ col,
    const float* __restrict__ inv, ushort_t* __restrict__ out, int n){
  int gw = (blockIdx.x * 256 + threadIdx.x) >> 5;
  int lane = threadIdx.x & 31;
  if (gw >= n) return;
  int s = row_ptr[gw], e = row_ptr[gw + 1];
  float ir = inv[gw];
  int off = lane * 4;
  float4 a0 = make_float4(0.f,0.f,0.f,0.f), a1 = make_float4(0.f,0.f,0.f,0.f);
  float4 a2 = make_float4(0.f,0.f,0.f,0.f), a3 = make_float4(0.f,0.f,0.f,0.f);
  int i = s;
  for (; i + 3 < e; i += 4){
    int c0 = col[i], c1 = col[i+1], c2 = col[i+2], c3 = col[i+3];
    ushort4 u0 = *(const ushort4*)(xb + (size_t)c0 * 128 + off);
    ushort4 u1 = *(const ushort4*)(xb + (size_t)c1 * 128 + off);
    ushort4 u2 = *(const ushort4*)(xb + (size_t)c2 * 128 + off);
    ushort4 u3 = *(const ushort4*)(xb + (size_t)c3 * 128 + off);
    a0.x += bf16_to_f(u0.x); a0.y += bf16_to_f(u0.y); a0.z += bf16_to_f(u0.z); a0.w += bf16_to_f(u0.w);
    a1.x += bf16_to_f(u1.x); a1.y += bf16_to_f(u1.y); a1.z += bf16_to_f(u1.z); a1.w += bf16_to_f(u1.w);
    a2.x += bf16_to_f(u2.x); a2.y += bf16_to_f(u2.y); a2.z += bf16_to_f(u2.z); a2.w += bf16_to_f(u2.w);
    a3.x += bf16_to_f(u3.x); a3.y += bf16_to_f(u3.y); a3.z += bf16_to_f(u3.z); a3.w += bf16_to_f(u3.w);
  }
  for (; i < e; ++i){
    int c0 = col[i];
    ushort4 u0 = *(const ushort4*)(xb + (size_t)c0 * 128 + off);
    a0.x += bf16_to_f(u0.x); a0.y += bf16_to_f(u0.y); a0.z += bf16_to_f(u0.z); a0.w += bf16_to_f(u0.w);
  }
  ushort4 ov;
  ov.x = bf16_rne(((a0.x + a1.x) + (a2.x + a3.x)) * ir);
  ov.y = bf16_rne(((a0.y + a1.y) + (a2.y + a3.y)) * ir);
  ov.z = bf16_rne(((a0.z + a1.z) + (a2.z + a3.z)) * ir);
  ov.w = bf16_rne(((a0.w + a1.w) + (a2.w + a3.w)) * ir);
  *(ushort4*)(out + (size_t)gw * 128 + off) = ov;
}

// s2 (bf16 [n][256]) -> h2 (bf16 [n][256]); h = leaky(inv * sum)
__global__ __launch_bounds__(256) void spmm256b_leaky_kernel(const ushort_t* __restrict__ sup,
    const int* __restrict__ row_ptr, const int* __restrict__ col,
    const float* __restrict__ inv, ushort_t* __restrict__ out, int n){
  int gw = (blockIdx.x * 256 + threadIdx.x) >> 6;
  int lane = threadIdx.x & 63;
  if (gw >= n) return;
  int s = row_ptr[gw], e = row_ptr[gw + 1];
  float ir = inv[gw];
  int off = lane * 4;
  float4 a0 = make_float4(0.f,0.f,0.f,0.f), a1 = make_float4(0.f,0.f,0.f,0.f);
  float4 a2 = make_float4(0.f,0.f,0.f,0.f), a3 = make_float4(0.f,0.f,0.f,0.f);
  int i = s;
  for (; i + 3 < e; i += 4){
    int c0 = col[i], c1 = col[i+1], c2 = col[i+2], c3 = col[i+3];
    ushort4 u0 = *(const ushort4*)(sup + (size_t)c0 * 256 + off);
    ushort4 u1 = *(const ushort4*)(sup + (size_t)c1 * 256 + off);
    ushort4 u2 = *(const ushort4*)(sup + (size_t)c2 * 256 + off);
    ushort4 u3 = *(const ushort4*)(sup + (size_t)c3 * 256 + off);
    a0.x += bf16_to_f(u0.x); a0.y += bf16_to_f(u0.y); a0.z += bf16_to_f(u0.z); a0.w += bf16_to_f(u0.w);
    a1.x += bf16_to_f(u1.x); a1.y += bf16_to_f(u1.y); a1.z += bf16_to_f(u1.z); a1.w += bf16_to_f(u1.w);
    a2.x += bf16_to_f(u2.x); a2.y += bf16_to_f(u2.y); a2.z += bf16_to_f(u2.z); a2.w += bf16_to_f(u2.w);
    a3.x += bf16_to_f(u3.x); a3.y += bf16_to_f(u3.y); a3.z += bf16_to_f(u3.z); a3.w += bf16_to_f(u3.w);
  }
  for (; i < e; ++i){
    int c0 = col[i];
    ushort4 u0 = *(const ushort4*)(sup + (size_t)c0 * 256 + off);
    a0.x += bf16_to_f(u0.x); a0.y += bf16_to_f(u0.y); a0.z += bf16_to_f(u0.z); a0.w += bf16_to_f(u0.w);
  }
  ushort4 ov;
  ov.x = bf16_rne(leaky(((a0.x + a1.x) + (a2.x + a3.x)) * ir));
  ov.y = bf16_rne(leaky(((a0.y + a1.y) + (a2.y + a3.y)) * ir));
  ov.z = bf16_rne(leaky(((a0.z + a1.z) + (a2.z + a3.z)) * ir));
  ov.w = bf16_rne(leaky(((a0.w + a1.w) + (a2.w + a3.w)) * ir));
  *(ushort4*)(out + (size_t)gw * 256 + off) = ov;
}

// s3 (bf16 [n][128]) -> out f32 [n][128]; inv-scale + L2 row-normalize
__global__ __launch_bounds__(256) void spmm_normb_kernel(const ushort_t* __restrict__ sup,
    const int* __restrict__ row_ptr, const int* __restrict__ col,
    const float* __restrict__ inv, float* __restrict__ out, int n){
  int gw = (blockIdx.x * 256 + threadIdx.x) >> 5;
  int lane = threadIdx.x & 31;
  if (gw >= n) return;
  int s = row_ptr[gw], e = row_ptr[gw + 1];
  float ir = inv[gw];
  int off = lane * 4;
  float4 a0 = make_float4(0.f,0.f,0.f,0.f), a1 = make_float4(0.f,0.f,0.f,0.f);
  float4 a2 = make_float4(0.f,0.f,0.f,0.f), a3 = make_float4(0.f,0.f,0.f,0.f);
  int i = s;
  for (; i + 3 < e; i += 4){
    int c0 = col[i], c1 = col[i+1], c2 = col[i+2], c3 = col[i+3];
    ushort4 u0 = *(const ushort4*)(sup + (size_t)c0 * 128 + off);
    ushort4 u1 = *(const ushort4*)(sup + (size_t)c1 * 128 + off);
    ushort4 u2 = *(const ushort4*)(sup + (size_t)c2 * 128 + off);
    ushort4 u3 = *(const ushort4*)(sup + (size_t)c3 * 128 + off);
    a0.x += bf16_to_f(u0.x); a0.y += bf16_to_f(u0.y); a0.z += bf16_to_f(u0.z); a0.w += bf16_to_f(u0.w);
    a1.x += bf16_to_f(u1.x); a1.y += bf16_to_f(u1.y); a1.z += bf16_to_f(u1.z); a1.w += bf16_to_f(u1.w);
    a2.x += bf16_to_f(u2.x); a2.y += bf16_to_f(u2.y); a2.z += bf16_to_f(u2.z); a2.w += bf16_to_f(u2.w);
    a3.x += bf16_to_f(u3.x); a3.y += bf16_to_f(u3.y); a3.z += bf16_to_f(u3.z); a3.w += bf16_to_f(u3.w);
  }
  for (; i < e; ++i){
    int c0 = col[i];
    ushort4 u0 = *(const ushort4*)(sup + (size_t)c0 * 128 + off);
    a0.x += bf16_to_f(u0.x); a0.y += bf16_to_f(u0.y); a0.z += bf16_to_f(u0.z); a0.w += bf16_to_f(u0.w);
  }
  float v0 = ((a0.x + a1.x) + (a2.x + a3.x)) * ir;
  float v1 = ((a0.y + a1.y) + (a2.y + a3.y)) * ir;
  float v2 = ((a0.z + a1.z) + (a2.z + a3.z)) * ir;
  float v3 = ((a0.w + a1.w) + (a2.w + a3.w)) * ir;
  float ss = v0*v0 + v1*v1 + v2*v2 + v3*v3;
  #pragma unroll
  for (int o = 16; o > 0; o >>= 1) ss += __shfl_xor(ss, o);
  float scale = 1.0f / fmaxf(sqrtf(ss), 1e-12f);
  float4 ov;
  ov.x = v0 * scale; ov.y = v1 * scale; ov.z = v2 * scale; ov.w = v3 * scale;
  *(float4*)(out + (size_t)gw * 128 + off) = ov;
}

// ---------------- launch ----------------

extern "C" void kernel_launch(void* const* d_in, const int* in_sizes, int n_in,
                              void* d_out, int out_size, void* d_ws, size_t ws_size,
                              hipStream_t stream){
  const float* x  = (const float*)d_in[0];
  const float* W1 = (const float*)d_in[1];
  const float* b1 = (const float*)d_in[2];
  const float* W2 = (const float*)d_in[3];
  const float* b2 = (const float*)d_in[4];
  const float* W3 = (const float*)d_in[5];
  const float* b3 = (const float*)d_in[6];
  const int* edges = (const int*)d_in[7];
  int N = in_sizes[0] / 128;
  int E = in_sizes[7] / 2;

  char* w = (char*)d_ws;
  size_t off = 0;
  auto alloc = [&](size_t bytes)->char*{
    char* p = w + off;
    off = (off + bytes + 255) & ~(size_t)255;
    return p;
  };
  int nBlocks = (N + 255) / 256;
  int*   deg     = (int*)  alloc((size_t)N * 4);
  float* inv     = (float*)alloc((size_t)N * 4);
  int*   row_ptr = (int*)  alloc(((size_t)N + 1) * 4);
  int*   cursor  = (int*)  alloc((size_t)N * 4);
  int*   colidx  = (int*)  alloc((size_t)E * 4);
  int*   partial = (int*)  alloc((size_t)nBlocks * 4);
  ushort_t* wt1h = (ushort_t*)alloc((size_t)128 * 256 * 2);
  ushort_t* wt1l = (ushort_t*)alloc((size_t)128 * 256 * 2);
  ushort_t* wt2h = (ushort_t*)alloc((size_t)256 * 256 * 2);
  ushort_t* wt2l = (ushort_t*)alloc((size_t)256 * 256 * 2);
  ushort_t* wt3h = (ushort_t*)alloc((size_t)256 * 128 * 2);
  ushort_t* wt3l = (ushort_t*)alloc((size_t)256 * 128 * 2);
  char* slabA = alloc((size_t)N * 1024);   // 51.2 MB
  char* slabB = alloc((size_t)N * 1024);   // 51.2 MB

  ushort_t* xb     = (ushort_t*)slabA;                       // [N][128] bf16
  ushort_t* t_buf  = (ushort_t*)(slabA + (size_t)N * 256);   // [N][128] bf16
  ushort_t* s2_buf = (ushort_t*)(slabA + (size_t)N * 512);   // [N][256] bf16
  ushort_t* h1_buf = (ushort_t*)slabB;                       // [N][256] bf16
  ushort_t* h2_buf = (ushort_t*)(slabB + (size_t)N * 512);   // [N][256] bf16
  ushort_t* s3_buf = (ushort_t*)slabA;                       // [N][128] bf16 (aliases dead xb)

  hipMemsetAsync(deg, 0, (size_t)N * 4, stream);
  int gE = (E + 255) / 256;
  deg_kernel<<<gE, 256, 0, stream>>>(edges, deg, E);
  scan_part_kernel<<<nBlocks, 256, 0, stream>>>(deg, partial, N);
  scan_top_kernel<<<1, 256, 0, stream>>>(partial, nBlocks);
  scan_fin_kernel<<<nBlocks, 256, 0, stream>>>(deg, partial, row_ptr, cursor, inv, N);
  scatter_kernel<<<gE, 256, 0, stream>>>(edges, cursor, colidx, E);
  sortrows_kernel<<<(N * 64 + 255) / 256, 256, 0, stream>>>(row_ptr, colidx, N);

  wprep_all_kernel<<<512, 256, 0, stream>>>(W1, W2, W3, wt1h, wt1l, wt2h, wt2l, wt3h, wt3l);
  xprep_kernel<<<(N * 128 / 8 + 255) / 256, 256, 0, stream>>>(x, xb, N * 128);

  int gm = (N + 127) / 128;
  dim3 g12(gm, 2);
  dim3 g3 (gm, 1);
  int gS64 = (N * 64 + 255) / 256;
  int gS32 = (N * 32 + 255) / 256;

  // layer 1 (reordered): t = A_hat xb ; h1 = bf16(leaky(t@W1 + mask*b1))
  spmm128b_kernel<<<gS32, 256, 0, stream>>>(xb, row_ptr, colidx, inv, t_buf, N);
  gemm_mfma_kernel<1><<<g12, 256, 0, stream>>>(t_buf, wt1h, wt1l, b1, inv,
                                               h1_buf, N, 128, 256);
  // layer 2: s2 = bf16(h1@W2 + b2) ; h2 = bf16(leaky(A_hat s2))
  gemm_mfma_kernel<2><<<g12, 256, 0, stream>>>(h1_buf, wt2h, wt2l, b2, nullptr,
                                               s2_buf, N, 256, 256);
  spmm256b_leaky_kernel<<<gS64, 256, 0, stream>>>(s2_buf, row_ptr, colidx, inv, h2_buf, N);
  // layer 3: s3 = bf16(h2@W3 + b3) ; out = normalize(A_hat s3)
  gemm_mfma_kernel<2><<<g3, 256, 0, stream>>>(h2_buf, wt3h, wt3l, b3, nullptr,
                                              s3_buf, N, 256, 128);
  spmm_normb_kernel<<<gS32, 256, 0, stream>>>(s3_buf, row_ptr, colidx, inv, (float*)d_out, N);
}

// Round 11
// 340.758 us; speedup vs baseline: 2.8561x; 1.0580x over previous
//
#include <hip/hip_runtime.h>

#define NEG_SLOPE 0.2f

typedef __attribute__((ext_vector_type(8))) short short8;
typedef __attribute__((ext_vector_type(4))) float floatx4;
typedef unsigned short ushort_t;

static __device__ __forceinline__ float leaky(float x){ return x > 0.f ? x : NEG_SLOPE * x; }

static __device__ __forceinline__ unsigned short bf16_rne(float x){
  unsigned u = __float_as_uint(x);
  unsigned r = (u + 0x7fffu + ((u >> 16) & 1u)) >> 16;
  return (unsigned short)r;
}
static __device__ __forceinline__ float bf16_to_f(unsigned short h){
  return __uint_as_float(((unsigned)h) << 16);
}

#define GLOAD_LDS16(g, l) \
  __builtin_amdgcn_global_load_lds((const __attribute__((address_space(1))) unsigned*)(g), \
                                   (__attribute__((address_space(3))) unsigned*)(l), 16, 0, 0)

// ---------------- CSR build ----------------

__global__ void deg_kernel(const int* __restrict__ edges, int* __restrict__ deg, int E){
  int i = blockIdx.x * 256 + threadIdx.x;
  if (i < E) atomicAdd(&deg[edges[2*i + 1]], 1);
}

__global__ __launch_bounds__(256) void scan_part_kernel(const int* __restrict__ deg,
                                                        int* __restrict__ partial, int n){
  int i = blockIdx.x * 256 + threadIdx.x;
  int v = (i < n) ? deg[i] : 0;
  #pragma unroll
  for (int o = 32; o > 0; o >>= 1) v += __shfl_xor(v, o);
  __shared__ int ws[4];
  if ((threadIdx.x & 63) == 0) ws[threadIdx.x >> 6] = v;
  __syncthreads();
  if (threadIdx.x == 0) partial[blockIdx.x] = ws[0] + ws[1] + ws[2] + ws[3];
}

__global__ __launch_bounds__(256) void scan_top_kernel(int* __restrict__ partial, int nb){
  int t = threadIdx.x;
  int lane = t & 63, w = t >> 6;
  int v = (t < nb) ? partial[t] : 0;
  int sc = v;
  #pragma unroll
  for (int o = 1; o < 64; o <<= 1){
    int x = __shfl_up(sc, o);
    if (lane >= o) sc += x;
  }
  __shared__ int wt[4];
  if (lane == 63) wt[w] = sc;
  __syncthreads();
  int base = 0;
  for (int j = 0; j < w; j++) base += wt[j];
  if (t < nb) partial[t] = base + sc - v;
}

__global__ __launch_bounds__(256) void scan_fin_kernel(const int* __restrict__ deg,
    const int* __restrict__ partial, int* __restrict__ row_ptr, int* __restrict__ cursor,
    float* __restrict__ inv, int n){
  int b = blockIdx.x, t = threadIdx.x;
  int i = b * 256 + t;
  int lane = t & 63, w = t >> 6;
  int v = (i < n) ? deg[i] : 0;
  int sc = v;
  #pragma unroll
  for (int o = 1; o < 64; o <<= 1){
    int x = __shfl_up(sc, o);
    if (lane >= o) sc += x;
  }
  __shared__ int wt[4];
  if (lane == 63) wt[w] = sc;
  __syncthreads();
  int base = partial[b];
  for (int j = 0; j < w; j++) base += wt[j];
  int excl = base + sc - v;
  if (i < n){
    row_ptr[i] = excl;
    cursor[i]  = excl;
    inv[i] = (v > 0) ? 1.0f / (float)v : 0.0f;
    if (i == n - 1) row_ptr[n] = excl + v;
  }
}

__global__ void scatter_kernel(const int* __restrict__ edges, int* __restrict__ cursor,
                               int* __restrict__ col, int E){
  int i = blockIdx.x * 256 + threadIdx.x;
  if (i < E){
    int s = edges[2*i], d = edges[2*i + 1];
    int p = atomicAdd(&cursor[d], 1);
    col[p] = s;
  }
}

// Deterministic col order per row (harness re-validates after replays; f32 sum
// order must be call-invariant). Wave-bitonic sort, all in registers.
__global__ __launch_bounds__(256) void sortrows_kernel(const int* __restrict__ row_ptr,
                                                       int* __restrict__ col, int n){
  int gw = (blockIdx.x * 256 + threadIdx.x) >> 6;
  int lane = threadIdx.x & 63;
  if (gw >= n) return;
  int s = row_ptr[gw], e = row_ptr[gw + 1];
  int len = e - s;
  if (len <= 1) return;
  if (len <= 64){
    int v = (lane < len) ? col[s + lane] : 0x7fffffff;
    #pragma unroll
    for (int k = 2; k <= 64; k <<= 1){
      #pragma unroll
      for (int j = k >> 1; j > 0; j >>= 1){
        int o = __shfl_xor(v, j);
        bool dirUp = ((lane & k) == 0);
        bool takeMin = (((lane & j) == 0) == dirUp);
        v = takeMin ? min(v, o) : max(v, o);
      }
    }
    if (lane < len) col[s + lane] = v;
  } else if (lane == 0){
    for (int i = s + 1; i < e; ++i){
      int v = col[i];
      int j = i - 1;
      while (j >= s && col[j] > v){ col[j + 1] = col[j]; --j; }
      col[j + 1] = v;
    }
  }
}

// ---------------- x -> bf16 ----------------

__global__ __launch_bounds__(256) void xprep_kernel(const float* __restrict__ x,
    ushort_t* __restrict__ xb, int total){
  int i = (blockIdx.x * 256 + threadIdx.x) * 8;
  if (i >= total) return;
  float4 a = *(const float4*)(x + i);
  float4 b = *(const float4*)(x + i + 4);
  short8 o;
  o[0] = (short)bf16_rne(a.x); o[1] = (short)bf16_rne(a.y);
  o[2] = (short)bf16_rne(a.z); o[3] = (short)bf16_rne(a.w);
  o[4] = (short)bf16_rne(b.x); o[5] = (short)bf16_rne(b.y);
  o[6] = (short)bf16_rne(b.z); o[7] = (short)bf16_rne(b.w);
  *(short8*)(xb + i) = o;
}

// ---------------- W prep (all 3 weights, one launch) ----------------
// W [K][N] f32 -> transposed bf16 [N][K] (single plane).

__global__ void wprep_all_kernel(const float* __restrict__ W1, const float* __restrict__ W2,
    const float* __restrict__ W3, ushort_t* __restrict__ t1,
    ushort_t* __restrict__ t2, ushort_t* __restrict__ t3){
  int i = blockIdx.x * 256 + threadIdx.x;
  const float* W; ushort_t* tp; int K, N, idx;
  if (i < 32768)      { W = W1; tp = t1; K = 128; N = 256; idx = i; }
  else if (i < 98304) { W = W2; tp = t2; K = 256; N = 256; idx = i - 32768; }
  else if (i < 131072){ W = W3; tp = t3; K = 256; N = 128; idx = i - 98304; }
  else return;
  int k = idx / N, n = idx - k * N;
  tp[(size_t)n * K + k] = bf16_rne(W[idx]);
}

// ---------------- MFMA GEMM (plain bf16 x bf16) ----------------
// A: [M][K] bf16, Bt: [N][K] bf16. f32 accum.
// 128x128 tile, 4 waves 2x2, BK=32, LDS double-buffered, one barrier/K-step
// (STAGE(t+1) -> COMPUTE(t) -> __syncthreads).
// K-major granule-plane LDS (conflict-free): each buf = A[4 gran][128 row]x16B
// (8KB) + B[4 gran][128 col]x16B (8KB); granule g holds k = g*8..g*8+7.
// Staged via global_load_lds, linear dest (chunk c -> plane c>>7, row c&127).
// MODE: 1 = bf16 out, leaky, bias masked by inv>0; 2 = bf16 out + bias.

template<int MODE>
__global__ __launch_bounds__(256) void gemm_mfma_kernel(
    const ushort_t* __restrict__ A, const ushort_t* __restrict__ Bt,
    const float* __restrict__ bias, const float* __restrict__ invv,
    ushort_t* __restrict__ Cp,
    int M, int K, int N){
  __shared__ ushort_t lds[2][8192];   // per buf: A 4096 u16 + B 4096 u16 = 16KB
  const int tid  = threadIdx.x;
  const int lane = tid & 63;
  const int wid  = tid >> 6;
  const int wrow = wid >> 1;
  const int wcol = wid & 1;
  const int br = blockIdx.x * 128;
  const int bc = blockIdx.y * 128;

  floatx4 acc[4][4];
  #pragma unroll
  for (int i = 0; i < 4; i++)
    #pragma unroll
    for (int j = 0; j < 4; j++) acc[i][j] = (floatx4){0.f, 0.f, 0.f, 0.f};

  auto STAGE = [&](int b, int k0){
    char* bufA = (char*)&lds[b][0];
    char* bufB = (char*)&lds[b][4096];
    #pragma unroll
    for (int q = 0; q < 2; q++){
      int c = q * 256 + tid;
      int g = c >> 7, r = c & 127;
      int grow = br + r;
      if (grow < M)
        GLOAD_LDS16(A + (size_t)grow * K + k0 + g * 8,
                    bufA + (q * 256 + wid * 64) * 16);
    }
    #pragma unroll
    for (int q = 0; q < 2; q++){
      int c = q * 256 + tid;
      int g = c >> 7, colc = c & 127;
      int gcol = bc + colc;
      GLOAD_LDS16(Bt + (size_t)gcol * K + k0 + g * 8,
                  bufB + (q * 256 + wid * 64) * 16);
    }
  };

  auto COMPUTE = [&](int b){
    const ushort_t* bufA = &lds[b][0];
    const ushort_t* bufB = &lds[b][4096];
    const int gsel = (lane >> 4) * 1024;   // granule plane, ushort units
    short8 bh[4];
    #pragma unroll
    for (int nf = 0; nf < 4; nf++)
      bh[nf] = *(const short8*)(bufB + gsel + (wcol * 64 + nf * 16 + (lane & 15)) * 8);
    #pragma unroll
    for (int mf = 0; mf < 4; mf++){
      short8 ah = *(const short8*)(bufA + gsel + (wrow * 64 + mf * 16 + (lane & 15)) * 8);
      #pragma unroll
      for (int nf = 0; nf < 4; nf++)
        acc[mf][nf] = __builtin_amdgcn_mfma_f32_16x16x32_bf16(ah, bh[nf], acc[mf][nf], 0, 0, 0);
    }
  };

  const int nt = K >> 5;
  STAGE(0, 0);
  __syncthreads();
  for (int t = 0; t < nt; ++t){
    if (t + 1 < nt) STAGE((t + 1) & 1, (t + 1) << 5);
    COMPUTE(t & 1);
    __syncthreads();
  }

  const int r0 = br + wrow * 64;
  const int c0 = bc + wcol * 64;
  #pragma unroll
  for (int nf = 0; nf < 4; nf++){
    int col = c0 + nf * 16 + (lane & 15);
    float bv = bias[col];
    #pragma unroll
    for (int mf = 0; mf < 4; mf++){
      int rbase = r0 + mf * 16 + ((lane >> 4) << 2);
      #pragma unroll
      for (int j = 0; j < 4; j++){
        int r = rbase + j;
        if (r >= M) continue;
        if (MODE == 1){
          float m = (invv[r] > 0.f) ? 1.f : 0.f;
          Cp[(size_t)r * N + col] = bf16_rne(leaky(acc[mf][nf][j] + m * bv));
        } else {
          Cp[(size_t)r * N + col] = bf16_rne(acc[mf][nf][j] + bv);
        }
      }
    }
  }
}

// ---------------- SpMM kernels (CSR gather, bf16 src, f32 accum) ----------------

// xb (bf16 [n][128]) -> t (bf16 [n][128]); t = inv * sum
__global__ __launch_bounds__(256) void spmm128b_kernel(const ushort_t* __restrict__ xb,
    const int* __restrict__ row_ptr, const int* __restrict__ col,
    const float* __restrict__ inv, ushort_t* __restrict__ out, int n){
  int gw = (blockIdx.x * 256 + threadIdx.x) >> 5;
  int lane = threadIdx.x & 31;
  if (gw >= n) return;
  int s = row_ptr[gw], e = row_ptr[gw + 1];
  float ir = inv[gw];
  int off = lane * 4;
  float4 a0 = make_float4(0.f,0.f,0.f,0.f), a1 = make_float4(0.f,0.f,0.f,0.f);
  float4 a2 = make_float4(0.f,0.f,0.f,0.f), a3 = make_float4(0.f,0.f,0.f,0.f);
  int i = s;
  for (; i + 3 < e; i += 4){
    int c0 = col[i], c1 = col[i+1], c2 = col[i+2], c3 = col[i+3];
    ushort4 u0 = *(const ushort4*)(xb + (size_t)c0 * 128 + off);
    ushort4 u1 = *(const ushort4*)(xb + (size_t)c1 * 128 + off);
    ushort4 u2 = *(const ushort4*)(xb + (size_t)c2 * 128 + off);
    ushort4 u3 = *(const ushort4*)(xb + (size_t)c3 * 128 + off);
    a0.x += bf16_to_f(u0.x); a0.y += bf16_to_f(u0.y); a0.z += bf16_to_f(u0.z); a0.w += bf16_to_f(u0.w);
    a1.x += bf16_to_f(u1.x); a1.y += bf16_to_f(u1.y); a1.z += bf16_to_f(u1.z); a1.w += bf16_to_f(u1.w);
    a2.x += bf16_to_f(u2.x); a2.y += bf16_to_f(u2.y); a2.z += bf16_to_f(u2.z); a2.w += bf16_to_f(u2.w);
    a3.x += bf16_to_f(u3.x); a3.y += bf16_to_f(u3.y); a3.z += bf16_to_f(u3.z); a3.w += bf16_to_f(u3.w);
  }
  for (; i < e; ++i){
    int c0 = col[i];
    ushort4 u0 = *(const ushort4*)(xb + (size_t)c0 * 128 + off);
    a0.x += bf16_to_f(u0.x); a0.y += bf16_to_f(u0.y); a0.z += bf16_to_f(u0.z); a0.w += bf16_to_f(u0.w);
  }
  ushort4 ov;
  ov.x = bf16_rne(((a0.x + a1.x) + (a2.x + a3.x)) * ir);
  ov.y = bf16_rne(((a0.y + a1.y) + (a2.y + a3.y)) * ir);
  ov.z = bf16_rne(((a0.z + a1.z) + (a2.z + a3.z)) * ir);
  ov.w = bf16_rne(((a0.w + a1.w) + (a2.w + a3.w)) * ir);
  *(ushort4*)(out + (size_t)gw * 128 + off) = ov;
}

// s2 (bf16 [n][256]) -> h2 (bf16 [n][256]); h = leaky(inv * sum)
__global__ __launch_bounds__(256) void spmm256b_leaky_kernel(const ushort_t* __restrict__ sup,
    const int* __restrict__ row_ptr, const int* __restrict__ col,
    const float* __restrict__ inv, ushort_t* __restrict__ out, int n){
  int gw = (blockIdx.x * 256 + threadIdx.x) >> 6;
  int lane = threadIdx.x & 63;
  if (gw >= n) return;
  int s = row_ptr[gw], e = row_ptr[gw + 1];
  float ir = inv[gw];
  int off = lane * 4;
  float4 a0 = make_float4(0.f,0.f,0.f,0.f), a1 = make_float4(0.f,0.f,0.f,0.f);
  float4 a2 = make_float4(0.f,0.f,0.f,0.f), a3 = make_float4(0.f,0.f,0.f,0.f);
  int i = s;
  for (; i + 3 < e; i += 4){
    int c0 = col[i], c1 = col[i+1], c2 = col[i+2], c3 = col[i+3];
    ushort4 u0 = *(const ushort4*)(sup + (size_t)c0 * 256 + off);
    ushort4 u1 = *(const ushort4*)(sup + (size_t)c1 * 256 + off);
    ushort4 u2 = *(const ushort4*)(sup + (size_t)c2 * 256 + off);
    ushort4 u3 = *(const ushort4*)(sup + (size_t)c3 * 256 + off);
    a0.x += bf16_to_f(u0.x); a0.y += bf16_to_f(u0.y); a0.z += bf16_to_f(u0.z); a0.w += bf16_to_f(u0.w);
    a1.x += bf16_to_f(u1.x); a1.y += bf16_to_f(u1.y); a1.z += bf16_to_f(u1.z); a1.w += bf16_to_f(u1.w);
    a2.x += bf16_to_f(u2.x); a2.y += bf16_to_f(u2.y); a2.z += bf16_to_f(u2.z); a2.w += bf16_to_f(u2.w);
    a3.x += bf16_to_f(u3.x); a3.y += bf16_to_f(u3.y); a3.z += bf16_to_f(u3.z); a3.w += bf16_to_f(u3.w);
  }
  for (; i < e; ++i){
    int c0 = col[i];
    ushort4 u0 = *(const ushort4*)(sup + (size_t)c0 * 256 + off);
    a0.x += bf16_to_f(u0.x); a0.y += bf16_to_f(u0.y); a0.z += bf16_to_f(u0.z); a0.w += bf16_to_f(u0.w);
  }
  ushort4 ov;
  ov.x = bf16_rne(leaky(((a0.x + a1.x) + (a2.x + a3.x)) * ir));
  ov.y = bf16_rne(leaky(((a0.y + a1.y) + (a2.y + a3.y)) * ir));
  ov.z = bf16_rne(leaky(((a0.z + a1.z) + (a2.z + a3.z)) * ir));
  ov.w = bf16_rne(leaky(((a0.w + a1.w) + (a2.w + a3.w)) * ir));
  *(ushort4*)(out + (size_t)gw * 256 + off) = ov;
}

// s3 (bf16 [n][128]) -> out f32 [n][128]; inv-scale + L2 row-normalize
__global__ __launch_bounds__(256) void spmm_normb_kernel(const ushort_t* __restrict__ sup,
    const int* __restrict__ row_ptr, const int* __restrict__ col,
    const float* __restrict__ inv, float* __restrict__ out, int n){
  int gw = (blockIdx.x * 256 + threadIdx.x) >> 5;
  int lane = threadIdx.x & 31;
  if (gw >= n) return;
  int s = row_ptr[gw], e = row_ptr[gw + 1];
  float ir = inv[gw];
  int off = lane * 4;
  float4 a0 = make_float4(0.f,0.f,0.f,0.f), a1 = make_float4(0.f,0.f,0.f,0.f);
  float4 a2 = make_float4(0.f,0.f,0.f,0.f), a3 = make_float4(0.f,0.f,0.f,0.f);
  int i = s;
  for (; i + 3 < e; i += 4){
    int c0 = col[i], c1 = col[i+1], c2 = col[i+2], c3 = col[i+3];
    ushort4 u0 = *(const ushort4*)(sup + (size_t)c0 * 128 + off);
    ushort4 u1 = *(const ushort4*)(sup + (size_t)c1 * 128 + off);
    ushort4 u2 = *(const ushort4*)(sup + (size_t)c2 * 128 + off);
    ushort4 u3 = *(const ushort4*)(sup + (size_t)c3 * 128 + off);
    a0.x += bf16_to_f(u0.x); a0.y += bf16_to_f(u0.y); a0.z += bf16_to_f(u0.z); a0.w += bf16_to_f(u0.w);
    a1.x += bf16_to_f(u1.x); a1.y += bf16_to_f(u1.y); a1.z += bf16_to_f(u1.z); a1.w += bf16_to_f(u1.w);
    a2.x += bf16_to_f(u2.x); a2.y += bf16_to_f(u2.y); a2.z += bf16_to_f(u2.z); a2.w += bf16_to_f(u2.w);
    a3.x += bf16_to_f(u3.x); a3.y += bf16_to_f(u3.y); a3.z += bf16_to_f(u3.z); a3.w += bf16_to_f(u3.w);
  }
  for (; i < e; ++i){
    int c0 = col[i];
    ushort4 u0 = *(const ushort4*)(sup + (size_t)c0 * 128 + off);
    a0.x += bf16_to_f(u0.x); a0.y += bf16_to_f(u0.y); a0.z += bf16_to_f(u0.z); a0.w += bf16_to_f(u0.w);
  }
  float v0 = ((a0.x + a1.x) + (a2.x + a3.x)) * ir;
  float v1 = ((a0.y + a1.y) + (a2.y + a3.y)) * ir;
  float v2 = ((a0.z + a1.z) + (a2.z + a3.z)) * ir;
  float v3 = ((a0.w + a1.w) + (a2.w + a3.w)) * ir;
  float ss = v0*v0 + v1*v1 + v2*v2 + v3*v3;
  #pragma unroll
  for (int o = 16; o > 0; o >>= 1) ss += __shfl_xor(ss, o);
  float scale = 1.0f / fmaxf(sqrtf(ss), 1e-12f);
  float4 ov;
  ov.x = v0 * scale; ov.y = v1 * scale; ov.z = v2 * scale; ov.w = v3 * scale;
  *(float4*)(out + (size_t)gw * 128 + off) = ov;
}

// ---------------- launch ----------------

extern "C" void kernel_launch(void* const* d_in, const int* in_sizes, int n_in,
                              void* d_out, int out_size, void* d_ws, size_t ws_size,
                              hipStream_t stream){
  const float* x  = (const float*)d_in[0];
  const float* W1 = (const float*)d_in[1];
  const float* b1 = (const float*)d_in[2];
  const float* W2 = (const float*)d_in[3];
  const float* b2 = (const float*)d_in[4];
  const float* W3 = (const float*)d_in[5];
  const float* b3 = (const float*)d_in[6];
  const int* edges = (const int*)d_in[7];
  int N = in_sizes[0] / 128;
  int E = in_sizes[7] / 2;

  char* w = (char*)d_ws;
  size_t off = 0;
  auto alloc = [&](size_t bytes)->char*{
    char* p = w + off;
    off = (off + bytes + 255) & ~(size_t)255;
    return p;
  };
  int nBlocks = (N + 255) / 256;
  int*   deg     = (int*)  alloc((size_t)N * 4);
  float* inv     = (float*)alloc((size_t)N * 4);
  int*   row_ptr = (int*)  alloc(((size_t)N + 1) * 4);
  int*   cursor  = (int*)  alloc((size_t)N * 4);
  int*   colidx  = (int*)  alloc((size_t)E * 4);
  int*   partial = (int*)  alloc((size_t)nBlocks * 4);
  ushort_t* wt1 = (ushort_t*)alloc((size_t)128 * 256 * 2);
  ushort_t* wt2 = (ushort_t*)alloc((size_t)256 * 256 * 2);
  ushort_t* wt3 = (ushort_t*)alloc((size_t)256 * 128 * 2);
  char* slabA = alloc((size_t)N * 1024);   // 51.2 MB
  char* slabB = alloc((size_t)N * 1024);   // 51.2 MB

  ushort_t* xb     = (ushort_t*)slabA;                       // [N][128] bf16
  ushort_t* t_buf  = (ushort_t*)(slabA + (size_t)N * 256);   // [N][128] bf16
  ushort_t* s2_buf = (ushort_t*)(slabA + (size_t)N * 512);   // [N][256] bf16
  ushort_t* h1_buf = (ushort_t*)slabB;                       // [N][256] bf16
  ushort_t* h2_buf = (ushort_t*)(slabB + (size_t)N * 512);   // [N][256] bf16
  ushort_t* s3_buf = (ushort_t*)slabA;                       // [N][128] bf16 (aliases dead xb)

  hipMemsetAsync(deg, 0, (size_t)N * 4, stream);
  int gE = (E + 255) / 256;
  deg_kernel<<<gE, 256, 0, stream>>>(edges, deg, E);
  scan_part_kernel<<<nBlocks, 256, 0, stream>>>(deg, partial, N);
  scan_top_kernel<<<1, 256, 0, stream>>>(partial, nBlocks);
  scan_fin_kernel<<<nBlocks, 256, 0, stream>>>(deg, partial, row_ptr, cursor, inv, N);
  scatter_kernel<<<gE, 256, 0, stream>>>(edges, cursor, colidx, E);
  sortrows_kernel<<<(N * 64 + 255) / 256, 256, 0, stream>>>(row_ptr, colidx, N);

  wprep_all_kernel<<<512, 256, 0, stream>>>(W1, W2, W3, wt1, wt2, wt3);
  xprep_kernel<<<(N * 128 / 8 + 255) / 256, 256, 0, stream>>>(x, xb, N * 128);

  int gm = (N + 127) / 128;
  dim3 g12(gm, 2);
  dim3 g3 (gm, 1);
  int gS64 = (N * 64 + 255) / 256;
  int gS32 = (N * 32 + 255) / 256;

  // layer 1 (reordered): t = A_hat xb ; h1 = bf16(leaky(t@W1 + mask*b1))
  spmm128b_kernel<<<gS32, 256, 0, stream>>>(xb, row_ptr, colidx, inv, t_buf, N);
  gemm_mfma_kernel<1><<<g12, 256, 0, stream>>>(t_buf, wt1, b1, inv, h1_buf, N, 128, 256);
  // layer 2: s2 = bf16(h1@W2 + b2) ; h2 = bf16(leaky(A_hat s2))
  gemm_mfma_kernel<2><<<g12, 256, 0, stream>>>(h1_buf, wt2, b2, nullptr, s2_buf, N, 256, 256);
  spmm256b_leaky_kernel<<<gS64, 256, 0, stream>>>(s2_buf, row_ptr, colidx, inv, h2_buf, N);
  // layer 3: s3 = bf16(h2@W3 + b3) ; out = normalize(A_hat s3)
  gemm_mfma_kernel<2><<<g3, 256, 0, stream>>>(h2_buf, wt3, b3, nullptr, s3_buf, N, 256, 128);
  spmm_normb_kernel<<<gS32, 256, 0, stream>>>(s3_buf, row_ptr, colidx, inv, (float*)d_out, N);
}